// Round 1
// baseline (777.506 us; speedup 1.0000x reference)
//
#include <hip/hip_runtime.h>
#include <hip/hip_bf16.h>
#include <math.h>

typedef __bf16 bf16_t;
typedef __bf16 bf16x8 __attribute__((ext_vector_type(8)));
typedef float f32x4 __attribute__((ext_vector_type(4)));

#define AS1 __attribute__((address_space(1)))
#define AS3 __attribute__((address_space(3)))

static constexpr int S_  = 2048;
static constexpr int HID = 4096;
static constexpr int NH  = 32;
static constexpr int HD  = 128;
static constexpr int N3  = 3 * HID;           // 12288
static constexpr float SCALE = 0.08838834764831845f;  // 1/sqrt(128)

// ---------------- fp32 -> bf16 convert (vectorized) ----------------
__global__ void cvt_f32_bf16(const float* __restrict__ in, bf16_t* __restrict__ out, int n4) {
  int i = blockIdx.x * blockDim.x + threadIdx.x;
  if (i >= n4) return;
  float4 v = ((const float4*)in)[i];
  union { bf16_t h[4]; short4 s4; } u;
  u.h[0] = (bf16_t)v.x; u.h[1] = (bf16_t)v.y; u.h[2] = (bf16_t)v.z; u.h[3] = (bf16_t)v.w;
  ((short4*)out)[i] = u.s4;
}

// ------------- transpose + convert: in[R][C] f32 -> out[C][R] bf16 -------------
__global__ void transcvt(const float* __restrict__ in, bf16_t* __restrict__ out, int R, int C) {
  __shared__ float t[32][33];
  int r0 = blockIdx.y * 32, c0 = blockIdx.x * 32;
  int tx = threadIdx.x, ty = threadIdx.y;  // 32 x 8
#pragma unroll
  for (int i = 0; i < 32; i += 8)
    t[ty + i][tx] = in[(size_t)(r0 + ty + i) * C + c0 + tx];
  __syncthreads();
#pragma unroll
  for (int i = 0; i < 32; i += 8)
    out[(size_t)(c0 + ty + i) * R + r0 + tx] = (bf16_t)t[tx][ty + i];
}

// ------- per-head V transpose: qkv[s][2*HID + h*HD + d] -> vt[(h*HD+d)*S + s] -------
__global__ void vtrans(const bf16_t* __restrict__ qkv, bf16_t* __restrict__ vt) {
  __shared__ bf16_t t[32][33];
  int h = blockIdx.z;
  int s0 = blockIdx.x * 32, d0 = blockIdx.y * 32;
  int tx = threadIdx.x, ty = threadIdx.y;  // 32 x 8
#pragma unroll
  for (int i = 0; i < 32; i += 8)
    t[ty + i][tx] = qkv[(size_t)(s0 + ty + i) * N3 + 2 * HID + h * HD + d0 + tx];
  __syncthreads();
#pragma unroll
  for (int i = 0; i < 32; i += 8)
    vt[(size_t)(h * HD + d0 + ty + i) * S_ + s0 + tx] = t[tx][ty + i];
}

// ---------------- m97-structure GEMM: C[M][N] = A[M][K] * BT[N][K]^T + bias ----------------
template <typename OutT>
__global__ __launch_bounds__(256) void gemm_bt(
    const bf16_t* __restrict__ A, const bf16_t* __restrict__ BT,
    const float* __restrict__ bias, OutT* __restrict__ C,
    int M, int N, int K) {
  __shared__ __align__(16) bf16_t As[128 * 32];
  __shared__ __align__(16) bf16_t Bs[128 * 32];
  const int tid = threadIdx.x;
  const int wv = tid >> 6, ln = tid & 63;
  const int m0 = blockIdx.y * 128, n0 = blockIdx.x * 128;
  const int wr = wv >> 1, wc = wv & 1;
  const int lr = ln & 15, lg = ln >> 4;

  f32x4 acc[4][4] = {};

  for (int k0 = 0; k0 < K; k0 += 32) {
    __syncthreads();
#pragma unroll
    for (int i = 0; i < 2; ++i) {
      const int o = (wv * 2 + i) * 1024 + ln * 16;  // linear byte offset in tile
      const int row = o >> 6;                       // 64B per row (32 bf16)
      const int col = (o & 63) >> 1;
      const bf16_t* ga = A + (size_t)(m0 + row) * K + k0 + col;
      const bf16_t* gb = BT + (size_t)(n0 + row) * K + k0 + col;
      __builtin_amdgcn_global_load_lds((const AS1 void*)ga,
                                       (AS3 void*)(As + (wv * 2 + i) * 512), 16, 0, 0);
      __builtin_amdgcn_global_load_lds((const AS1 void*)gb,
                                       (AS3 void*)(Bs + (wv * 2 + i) * 512), 16, 0, 0);
    }
    __syncthreads();
    bf16x8 a[4], b[4];
#pragma unroll
    for (int mi = 0; mi < 4; ++mi)
      a[mi] = *(const bf16x8*)&As[(64 * wr + 16 * mi + lr) * 32 + lg * 8];
#pragma unroll
    for (int ni = 0; ni < 4; ++ni)
      b[ni] = *(const bf16x8*)&Bs[(64 * wc + 16 * ni + lr) * 32 + lg * 8];
#pragma unroll
    for (int mi = 0; mi < 4; ++mi)
#pragma unroll
      for (int ni = 0; ni < 4; ++ni)
        acc[mi][ni] = __builtin_amdgcn_mfma_f32_16x16x32_bf16(a[mi], b[ni], acc[mi][ni], 0, 0, 0);
  }

#pragma unroll
  for (int mi = 0; mi < 4; ++mi)
#pragma unroll
    for (int ni = 0; ni < 4; ++ni) {
      const int col = n0 + 64 * wc + 16 * ni + lr;
      const float bv = bias[col];
#pragma unroll
      for (int i = 0; i < 4; ++i) {
        const int row = m0 + 64 * wr + 16 * mi + lg * 4 + i;
        C[(size_t)row * N + col] = (OutT)(acc[mi][ni][i] + bv);
      }
    }
}

// ---------------- flash attention: causal, 32 heads, d=128 ----------------
// block = (q-tile of 64 rows, head); 4 waves x 16 rows each; KV tile = 64
__global__ __launch_bounds__(256) void attn_fwd(
    const bf16_t* __restrict__ qkv, const bf16_t* __restrict__ vt,
    bf16_t* __restrict__ ctx) {
  __shared__ __align__(16) bf16_t Ks[64][136];    // K rows (kv), padded (272B stride)
  __shared__ __align__(16) bf16_t Vts[128][72];   // V^T rows (d), padded (144B stride)
  __shared__ __align__(16) bf16_t Plds[4][16][72];

  const int tid = threadIdx.x;
  const int wv = tid >> 6, ln = tid & 63;
  const int qt = blockIdx.x, h = blockIdx.y;
  const int q0 = qt * 64;
  const int lr = ln & 15, lg = ln >> 4;

  // Q fragments: rows q0 + 16*wv + lr, k = kk*32 + lg*8 .. +8
  bf16x8 qf[4];
#pragma unroll
  for (int kk = 0; kk < 4; ++kk)
    qf[kk] = *(const bf16x8*)(qkv + (size_t)(q0 + 16 * wv + lr) * N3 + h * HD + kk * 32 + lg * 8);

  f32x4 oacc[8] = {};
  float mrow[4], lsum[4];
#pragma unroll
  for (int i = 0; i < 4; ++i) { mrow[i] = -INFINITY; lsum[i] = 0.f; }

  const int ntiles = qt + 1;
  for (int t = 0; t < ntiles; ++t) {
    const int kv0 = t * 64;
    __syncthreads();
    // stage K (64x128) and Vt (128x64), 16B chunks, coalesced
#pragma unroll
    for (int it = 0; it < 4; ++it) {
      int c = tid + it * 256;
      {
        int row = c >> 4, col = (c & 15) * 8;
        *(bf16x8*)&Ks[row][col] =
            *(const bf16x8*)(qkv + (size_t)(kv0 + row) * N3 + HID + h * HD + col);
      }
      {
        int row = c >> 3, col = (c & 7) * 8;
        *(bf16x8*)&Vts[row][col] =
            *(const bf16x8*)(vt + (size_t)(h * HD + row) * S_ + kv0 + col);
      }
    }
    __syncthreads();

    // S = Q K^T
    f32x4 sacc[4] = {};
#pragma unroll
    for (int kk = 0; kk < 4; ++kk)
#pragma unroll
      for (int ni = 0; ni < 4; ++ni) {
        bf16x8 kf = *(const bf16x8*)&Ks[16 * ni + lr][kk * 32 + lg * 8];
        sacc[ni] = __builtin_amdgcn_mfma_f32_16x16x32_bf16(qf[kk], kf, sacc[ni], 0, 0, 0);
      }

    // online softmax (fp32), row r held by 16-lane group: row = lg*4 + i, col = 16*ni + lr
    float p[4][4];
    float alpha[4];
#pragma unroll
    for (int i = 0; i < 4; ++i) {
      const int row = q0 + 16 * wv + lg * 4 + i;
      float mx = -INFINITY;
#pragma unroll
      for (int ni = 0; ni < 4; ++ni) {
        float s = sacc[ni][i] * SCALE;
        if (kv0 + 16 * ni + lr > row) s = -INFINITY;
        p[ni][i] = s;
        mx = fmaxf(mx, s);
      }
      mx = fmaxf(mx, __shfl_xor(mx, 1, 64));
      mx = fmaxf(mx, __shfl_xor(mx, 2, 64));
      mx = fmaxf(mx, __shfl_xor(mx, 4, 64));
      mx = fmaxf(mx, __shfl_xor(mx, 8, 64));
      const float mn = fmaxf(mrow[i], mx);
      alpha[i] = __expf(mrow[i] - mn);   // exp(-inf)=0 on first tile
      mrow[i] = mn;
      float ps = 0.f;
#pragma unroll
      for (int ni = 0; ni < 4; ++ni) {
        float e = __expf(p[ni][i] - mn);
        p[ni][i] = e;
        ps += e;
      }
      ps += __shfl_xor(ps, 1, 64);
      ps += __shfl_xor(ps, 2, 64);
      ps += __shfl_xor(ps, 4, 64);
      ps += __shfl_xor(ps, 8, 64);
      lsum[i] = lsum[i] * alpha[i] + ps;
    }
#pragma unroll
    for (int nf = 0; nf < 8; ++nf)
#pragma unroll
      for (int i = 0; i < 4; ++i) oacc[nf][i] *= alpha[i];

    // P (C-layout) -> LDS -> A-fragment layout
#pragma unroll
    for (int ni = 0; ni < 4; ++ni)
#pragma unroll
      for (int i = 0; i < 4; ++i)
        Plds[wv][lg * 4 + i][16 * ni + lr] = (bf16_t)p[ni][i];
    __syncthreads();

    // PV: oacc[nf] += P[16x64] * V[64x128]
#pragma unroll
    for (int kk2 = 0; kk2 < 2; ++kk2) {
      bf16x8 pf = *(const bf16x8*)&Plds[wv][lr][kk2 * 32 + lg * 8];
#pragma unroll
      for (int nf = 0; nf < 8; ++nf) {
        bf16x8 vf = *(const bf16x8*)&Vts[16 * nf + lr][kk2 * 32 + lg * 8];
        oacc[nf] = __builtin_amdgcn_mfma_f32_16x16x32_bf16(pf, vf, oacc[nf], 0, 0, 0);
      }
    }
  }

  // epilogue: ctx[row][h*HD + col] = oacc / l
#pragma unroll
  for (int nf = 0; nf < 8; ++nf)
#pragma unroll
    for (int i = 0; i < 4; ++i) {
      int row = q0 + 16 * wv + lg * 4 + i;
      int col = h * HD + 16 * nf + lr;
      ctx[(size_t)row * HID + col] = (bf16_t)(oacc[nf][i] / lsum[i]);
    }
}

// ---------------- launcher ----------------
extern "C" void kernel_launch(void* const* d_in, const int* in_sizes, int n_in,
                              void* d_out, int out_size, void* d_ws, size_t ws_size,
                              hipStream_t stream) {
  const float* x    = (const float*)d_in[0];
  const float* wqkv = (const float*)d_in[1];
  const float* bqkv = (const float*)d_in[2];
  const float* ow   = (const float*)d_in[3];
  const float* ob   = (const float*)d_in[4];
  float* out = (float*)d_out;

  char* w = (char*)d_ws;
  bf16_t* xb    = (bf16_t*)(w);                          // S*HID       bf16 (16 MB)
  bf16_t* wqkvT = (bf16_t*)(w + (size_t)16777216);       // N3*HID      bf16 (100.7 MB)
  bf16_t* qkv   = (bf16_t*)(w + (size_t)117440512);      // S*N3        bf16 (50.3 MB)
  bf16_t* vt    = (bf16_t*)(w + (size_t)167772160);      // NH*HD*S     bf16 (16 MB)
  bf16_t* ctx   = (bf16_t*)(w + (size_t)184549376);      // S*HID       bf16 (16 MB)
  bf16_t* owT   = (bf16_t*)(w + (size_t)201326592);      // HID*HID     bf16 (33.6 MB)

  (void)in_sizes; (void)n_in; (void)out_size; (void)ws_size;

  // 1) convert x to bf16
  cvt_f32_bf16<<<(S_ * HID / 4 + 255) / 256, 256, 0, stream>>>(x, xb, S_ * HID / 4);
  // 2) transpose+convert weights to bf16 [N][K]
  transcvt<<<dim3(N3 / 32, HID / 32), dim3(32, 8), 0, stream>>>(wqkv, wqkvT, HID, N3);
  transcvt<<<dim3(HID / 32, HID / 32), dim3(32, 8), 0, stream>>>(ow, owT, HID, HID);
  // 3) QKV projection
  gemm_bt<bf16_t><<<dim3(N3 / 128, S_ / 128), 256, 0, stream>>>(xb, wqkvT, bqkv, qkv, S_, N3, HID);
  // 4) per-head V transpose
  vtrans<<<dim3(S_ / 32, HD / 32, NH), dim3(32, 8), 0, stream>>>(qkv, vt);
  // 5) flash attention
  attn_fwd<<<dim3(S_ / 64, NH), 256, 0, stream>>>(qkv, vt, ctx);
  // 6) output projection
  gemm_bt<float><<<dim3(HID / 128, S_ / 128), 256, 0, stream>>>(ctx, owT, ob, out, S_, HID, HID);
}

// Round 2
// 660.605 us; speedup vs baseline: 1.1770x; 1.1770x over previous
//
#include <hip/hip_runtime.h>
#include <hip/hip_bf16.h>
#include <math.h>

typedef __bf16 bf16_t;
typedef __bf16 bf16x8 __attribute__((ext_vector_type(8)));
typedef float f32x4 __attribute__((ext_vector_type(4)));

#define AS1 __attribute__((address_space(1)))
#define AS3 __attribute__((address_space(3)))

static constexpr int S_  = 2048;
static constexpr int HID = 4096;
static constexpr int NH  = 32;
static constexpr int HD  = 128;
static constexpr int N3  = 3 * HID;           // 12288
static constexpr float SCALE = 0.08838834764831845f;  // 1/sqrt(128)

// ---------------- fp32 -> bf16 convert (vectorized) ----------------
__global__ void cvt_f32_bf16(const float* __restrict__ in, bf16_t* __restrict__ out, int n4) {
  int i = blockIdx.x * blockDim.x + threadIdx.x;
  if (i >= n4) return;
  float4 v = ((const float4*)in)[i];
  union { bf16_t h[4]; short4 s4; } u;
  u.h[0] = (bf16_t)v.x; u.h[1] = (bf16_t)v.y; u.h[2] = (bf16_t)v.z; u.h[3] = (bf16_t)v.w;
  ((short4*)out)[i] = u.s4;
}

// ------------- transpose + convert: in[R][C] f32 -> out[C][R] bf16 -------------
__global__ void transcvt(const float* __restrict__ in, bf16_t* __restrict__ out, int R, int C) {
  __shared__ float t[32][33];
  int r0 = blockIdx.y * 32, c0 = blockIdx.x * 32;
  int tx = threadIdx.x, ty = threadIdx.y;  // 32 x 8
#pragma unroll
  for (int i = 0; i < 32; i += 8)
    t[ty + i][tx] = in[(size_t)(r0 + ty + i) * C + c0 + tx];
  __syncthreads();
#pragma unroll
  for (int i = 0; i < 32; i += 8)
    out[(size_t)(c0 + ty + i) * R + r0 + tx] = (bf16_t)t[tx][ty + i];
}

// ------- per-head V transpose: qkv[s][2*HID + h*HD + d] -> vt[(h*HD+d)*S + s] -------
__global__ void vtrans(const bf16_t* __restrict__ qkv, bf16_t* __restrict__ vt) {
  __shared__ bf16_t t[32][33];
  int h = blockIdx.z;
  int s0 = blockIdx.x * 32, d0 = blockIdx.y * 32;
  int tx = threadIdx.x, ty = threadIdx.y;  // 32 x 8
#pragma unroll
  for (int i = 0; i < 32; i += 8)
    t[ty + i][tx] = qkv[(size_t)(s0 + ty + i) * N3 + 2 * HID + h * HD + d0 + tx];
  __syncthreads();
#pragma unroll
  for (int i = 0; i < 32; i += 8)
    vt[(size_t)(h * HD + d0 + ty + i) * S_ + s0 + tx] = t[tx][ty + i];
}

// ---------------- m97-structure GEMM: C[M][N] = A[M][K] * BT[N][K]^T + bias ----------------
// Flat 1D grid + bijective XCD swizzle (T1): nwg must be a multiple of 8.
template <typename OutT>
__global__ __launch_bounds__(256) void gemm_bt(
    const bf16_t* __restrict__ A, const bf16_t* __restrict__ BT,
    const float* __restrict__ bias, OutT* __restrict__ C,
    int M, int N, int K) {
  __shared__ __align__(16) bf16_t As[128 * 32];
  __shared__ __align__(16) bf16_t Bs[128 * 32];
  const int tid = threadIdx.x;
  const int wv = tid >> 6, ln = tid & 63;

  const int nx = N >> 7;
  const int nwg = gridDim.x;
  const int qx = nwg >> 3;
  const int wg = (blockIdx.x & 7) * qx + (blockIdx.x >> 3);  // XCD-contiguous chunks
  const int m0 = (wg / nx) * 128, n0 = (wg % nx) * 128;

  const int wr = wv >> 1, wc = wv & 1;
  const int lr = ln & 15, lg = ln >> 4;

  f32x4 acc[4][4] = {};

  for (int k0 = 0; k0 < K; k0 += 32) {
    __syncthreads();
#pragma unroll
    for (int i = 0; i < 2; ++i) {
      const int o = (wv * 2 + i) * 1024 + ln * 16;  // linear byte offset in tile
      const int row = o >> 6;                       // 64B per row (32 bf16)
      const int col = (o & 63) >> 1;
      const bf16_t* ga = A + (size_t)(m0 + row) * K + k0 + col;
      const bf16_t* gb = BT + (size_t)(n0 + row) * K + k0 + col;
      __builtin_amdgcn_global_load_lds((const AS1 void*)ga,
                                       (AS3 void*)(As + (wv * 2 + i) * 512), 16, 0, 0);
      __builtin_amdgcn_global_load_lds((const AS1 void*)gb,
                                       (AS3 void*)(Bs + (wv * 2 + i) * 512), 16, 0, 0);
    }
    __syncthreads();
    bf16x8 a[4], b[4];
#pragma unroll
    for (int mi = 0; mi < 4; ++mi)
      a[mi] = *(const bf16x8*)&As[(64 * wr + 16 * mi + lr) * 32 + lg * 8];
#pragma unroll
    for (int ni = 0; ni < 4; ++ni)
      b[ni] = *(const bf16x8*)&Bs[(64 * wc + 16 * ni + lr) * 32 + lg * 8];
#pragma unroll
    for (int mi = 0; mi < 4; ++mi)
#pragma unroll
      for (int ni = 0; ni < 4; ++ni)
        acc[mi][ni] = __builtin_amdgcn_mfma_f32_16x16x32_bf16(a[mi], b[ni], acc[mi][ni], 0, 0, 0);
  }

#pragma unroll
  for (int mi = 0; mi < 4; ++mi)
#pragma unroll
    for (int ni = 0; ni < 4; ++ni) {
      const int col = n0 + 64 * wc + 16 * ni + lr;
      const float bv = bias[col];
#pragma unroll
      for (int i = 0; i < 4; ++i) {
        const int row = m0 + 64 * wr + 16 * mi + lg * 4 + i;
        C[(size_t)row * N + col] = (OutT)(acc[mi][ni][i] + bv);
      }
    }
}

// ---------------- flash attention: causal, 32 heads, d=128 ----------------
// block = (q-tile of 64 rows, head); 4 waves x 16 rows each; KV tile = 64
// LDS: Ks (17.4KB, P overlaid after QK barrier) + Vts (18.4KB) = 35.8KB -> 4 blocks/CU
__global__ __launch_bounds__(256, 4) void attn_fwd(
    const bf16_t* __restrict__ qkv, const bf16_t* __restrict__ vt,
    bf16_t* __restrict__ ctx) {
  __shared__ __align__(16) bf16_t Ks[64][136];    // K rows (kv), 272B stride
  __shared__ __align__(16) bf16_t Vts[128][72];   // V^T rows (d), 144B stride

  const int tid = threadIdx.x;
  const int wv = tid >> 6, ln = tid & 63;
  // P buffer overlaid on Ks: per-wave [16][72] slice (4*2304B = 9216B <= 17408B)
  bf16_t* Pl = &Ks[0][0] + wv * (16 * 72);

  // block decode: XCD-clustered heads + balanced causal work.
  // bid = x + 8*a + 256*b (x=0..7 XCD under round-robin, a=0..31, b=0..3)
  // h = 4x+b (4 heads per XCD -> K/V panels stay in that XCD's L2)
  // qt spread with a+8b so blocks co-resident on a CU get mixed tile counts
  const int bid = blockIdx.x;
  const int h  = ((bid & 7) << 2) + (bid >> 8);
  const int qt = 31 - ((((bid >> 3) & 31) + ((bid >> 8) << 3)) & 31);
  const int q0 = qt * 64;
  const int lr = ln & 15, lg = ln >> 4;

  // Q fragments with softmax scale folded in (bf16 rounding: ~0.2% rel err, ok)
  bf16x8 qf[4];
#pragma unroll
  for (int kk = 0; kk < 4; ++kk) {
    bf16x8 r = *(const bf16x8*)(qkv + (size_t)(q0 + 16 * wv + lr) * N3 + h * HD + kk * 32 + lg * 8);
#pragma unroll
    for (int j = 0; j < 8; ++j) r[j] = (bf16_t)((float)r[j] * SCALE);
    qf[kk] = r;
  }

  f32x4 oacc[8] = {};
  float mrow[4], psum[4];
#pragma unroll
  for (int i = 0; i < 4; ++i) { mrow[i] = -INFINITY; psum[i] = 0.f; }

  const int ntiles = qt + 1;
  for (int t = 0; t < ntiles; ++t) {
    const int kv0 = t * 64;
    __syncthreads();  // prev iter's PV reads of Vts/Pl(=Ks) done before restaging
    // stage K (64x128) and Vt (128x64), 16B chunks, coalesced
#pragma unroll
    for (int it = 0; it < 4; ++it) {
      int c = tid + it * 256;
      {
        int row = c >> 4, col = (c & 15) * 8;
        *(bf16x8*)&Ks[row][col] =
            *(const bf16x8*)(qkv + (size_t)(kv0 + row) * N3 + HID + h * HD + col);
      }
      {
        int row = c >> 3, col = (c & 7) * 8;
        *(bf16x8*)&Vts[row][col] =
            *(const bf16x8*)(vt + (size_t)(h * HD + row) * S_ + kv0 + col);
      }
    }
    __syncthreads();

    // S = Q K^T (scale already folded into Q)
    f32x4 sacc[4] = {};
#pragma unroll
    for (int kk = 0; kk < 4; ++kk)
#pragma unroll
      for (int ni = 0; ni < 4; ++ni) {
        bf16x8 kf = *(const bf16x8*)&Ks[16 * ni + lr][kk * 32 + lg * 8];
        sacc[ni] = __builtin_amdgcn_mfma_f32_16x16x32_bf16(qf[kk], kf, sacc[ni], 0, 0, 0);
      }

    // online softmax; row (per 16-lane group) = q0+16wv+lg*4+i, col = kv0+16ni+lr
    const bool needmask = (kv0 + 63 > q0 + 16 * wv);  // wave-uniform
    float p[4][4];
    float mx[4];
    bool grow = false;
#pragma unroll
    for (int i = 0; i < 4; ++i) {
      const int row = q0 + 16 * wv + lg * 4 + i;
      float m_ = -INFINITY;
#pragma unroll
      for (int ni = 0; ni < 4; ++ni) {
        float s = sacc[ni][i];
        if (needmask && (kv0 + 16 * ni + lr > row)) s = -INFINITY;
        p[ni][i] = s;
        m_ = fmaxf(m_, s);
      }
      m_ = fmaxf(m_, __shfl_xor(m_, 1, 64));
      m_ = fmaxf(m_, __shfl_xor(m_, 2, 64));
      m_ = fmaxf(m_, __shfl_xor(m_, 4, 64));
      m_ = fmaxf(m_, __shfl_xor(m_, 8, 64));
      mx[i] = m_;
      grow |= (m_ > mrow[i]);
    }
    if (__any(grow)) {  // rescale only when a row max grew (T13-lite)
      float alpha[4];
#pragma unroll
      for (int i = 0; i < 4; ++i) {
        const float mn = fmaxf(mrow[i], mx[i]);
        alpha[i] = __expf(mrow[i] - mn);  // exp(-inf)=0 on first tile
        mrow[i] = mn;
        psum[i] *= alpha[i];
      }
#pragma unroll
      for (int nf = 0; nf < 8; ++nf)
#pragma unroll
        for (int i = 0; i < 4; ++i) oacc[nf][i] *= alpha[i];
    }
#pragma unroll
    for (int i = 0; i < 4; ++i) {
      float ps = 0.f;
#pragma unroll
      for (int ni = 0; ni < 4; ++ni) {
        float e = __expf(p[ni][i] - mrow[i]);
        p[ni][i] = e;
        ps += e;
      }
      psum[i] += ps;  // lane-local partial; cross-lane reduce deferred to epilogue
    }

    __syncthreads();  // all waves done reading Ks -> safe to overwrite with P

    // P (C-layout) -> per-wave LDS slice -> A-fragment layout
#pragma unroll
    for (int ni = 0; ni < 4; ++ni)
#pragma unroll
      for (int i = 0; i < 4; ++i)
        Pl[(lg * 4 + i) * 72 + 16 * ni + lr] = (bf16_t)p[ni][i];
    // same-wave write->read: compiler inserts lgkmcnt wait, no barrier needed

    // PV: oacc[nf] += P[16x64] * V[64x128]
#pragma unroll
    for (int kk2 = 0; kk2 < 2; ++kk2) {
      bf16x8 pf = *(const bf16x8*)&Pl[lr * 72 + kk2 * 32 + lg * 8];
#pragma unroll
      for (int nf = 0; nf < 8; ++nf) {
        bf16x8 vf = *(const bf16x8*)&Vts[16 * nf + lr][kk2 * 32 + lg * 8];
        oacc[nf] = __builtin_amdgcn_mfma_f32_16x16x32_bf16(pf, vf, oacc[nf], 0, 0, 0);
      }
    }
  }

  // epilogue: reduce row sums across the 16 lanes of each lg-group, then normalize
#pragma unroll
  for (int i = 0; i < 4; ++i) {
    float s = psum[i];
    s += __shfl_xor(s, 1, 64);
    s += __shfl_xor(s, 2, 64);
    s += __shfl_xor(s, 4, 64);
    s += __shfl_xor(s, 8, 64);
    psum[i] = 1.f / s;
  }
#pragma unroll
  for (int nf = 0; nf < 8; ++nf)
#pragma unroll
    for (int i = 0; i < 4; ++i) {
      int row = q0 + 16 * wv + lg * 4 + i;
      int col = h * HD + 16 * nf + lr;
      ctx[(size_t)row * HID + col] = (bf16_t)(oacc[nf][i] * psum[i]);
    }
}

// ---------------- launcher ----------------
extern "C" void kernel_launch(void* const* d_in, const int* in_sizes, int n_in,
                              void* d_out, int out_size, void* d_ws, size_t ws_size,
                              hipStream_t stream) {
  const float* x    = (const float*)d_in[0];
  const float* wqkv = (const float*)d_in[1];
  const float* bqkv = (const float*)d_in[2];
  const float* ow   = (const float*)d_in[3];
  const float* ob   = (const float*)d_in[4];
  float* out = (float*)d_out;

  char* w = (char*)d_ws;
  bf16_t* xb    = (bf16_t*)(w);                          // S*HID       bf16 (16 MB)
  bf16_t* wqkvT = (bf16_t*)(w + (size_t)16777216);       // N3*HID      bf16 (100.7 MB)
  bf16_t* qkv   = (bf16_t*)(w + (size_t)117440512);      // S*N3        bf16 (50.3 MB)
  bf16_t* vt    = (bf16_t*)(w + (size_t)167772160);      // NH*HD*S     bf16 (16 MB)
  bf16_t* ctx   = (bf16_t*)(w + (size_t)184549376);      // S*HID       bf16 (16 MB)
  bf16_t* owT   = (bf16_t*)(w + (size_t)201326592);      // HID*HID     bf16 (33.6 MB)

  (void)in_sizes; (void)n_in; (void)out_size; (void)ws_size;

  // 1) convert x to bf16
  cvt_f32_bf16<<<(S_ * HID / 4 + 255) / 256, 256, 0, stream>>>(x, xb, S_ * HID / 4);
  // 2) transpose+convert weights to bf16 [N][K]
  transcvt<<<dim3(N3 / 32, HID / 32), dim3(32, 8), 0, stream>>>(wqkv, wqkvT, HID, N3);
  transcvt<<<dim3(HID / 32, HID / 32), dim3(32, 8), 0, stream>>>(ow, owT, HID, HID);
  // 3) QKV projection  (flat grid: 96*16 = 1536 blocks, %8==0)
  gemm_bt<bf16_t><<<(N3 / 128) * (S_ / 128), 256, 0, stream>>>(xb, wqkvT, bqkv, qkv, S_, N3, HID);
  // 4) per-head V transpose
  vtrans<<<dim3(S_ / 32, HD / 32, NH), dim3(32, 8), 0, stream>>>(qkv, vt);
  // 5) flash attention (1024 blocks = 4/CU, all resident)
  attn_fwd<<<(S_ / 64) * NH, 256, 0, stream>>>(qkv, vt, ctx);
  // 6) output projection (flat grid: 32*16 = 512 blocks, %8==0)
  gemm_bt<float><<<(HID / 128) * (S_ / 128), 256, 0, stream>>>(ctx, owT, ob, out, S_, HID, HID);
}

// Round 3
// 585.043 us; speedup vs baseline: 1.3290x; 1.1292x over previous
//
#include <hip/hip_runtime.h>
#include <hip/hip_bf16.h>
#include <math.h>

typedef __bf16 bf16_t;
typedef __bf16 bf16x8 __attribute__((ext_vector_type(8)));
typedef float f32x4 __attribute__((ext_vector_type(4)));

#define AS1 __attribute__((address_space(1)))
#define AS3 __attribute__((address_space(3)))

static constexpr int S_  = 2048;
static constexpr int HID = 4096;
static constexpr int NH  = 32;
static constexpr int HD  = 128;
static constexpr int N3  = 3 * HID;           // 12288
static constexpr float SCALE = 0.08838834764831845f;  // 1/sqrt(128)

// ---------------- fp32 -> bf16 convert (vectorized) ----------------
__global__ void cvt_f32_bf16(const float* __restrict__ in, bf16_t* __restrict__ out, int n4) {
  int i = blockIdx.x * blockDim.x + threadIdx.x;
  if (i >= n4) return;
  float4 v = ((const float4*)in)[i];
  union { bf16_t h[4]; short4 s4; } u;
  u.h[0] = (bf16_t)v.x; u.h[1] = (bf16_t)v.y; u.h[2] = (bf16_t)v.z; u.h[3] = (bf16_t)v.w;
  ((short4*)out)[i] = u.s4;
}

// ------------- transpose + convert: in[R][C] f32 -> out[C][R] bf16 -------------
__global__ void transcvt(const float* __restrict__ in, bf16_t* __restrict__ out, int R, int C) {
  __shared__ float t[32][33];
  int r0 = blockIdx.y * 32, c0 = blockIdx.x * 32;
  int tx = threadIdx.x, ty = threadIdx.y;  // 32 x 8
#pragma unroll
  for (int i = 0; i < 32; i += 8)
    t[ty + i][tx] = in[(size_t)(r0 + ty + i) * C + c0 + tx];
  __syncthreads();
#pragma unroll
  for (int i = 0; i < 32; i += 8)
    out[(size_t)(c0 + ty + i) * R + r0 + tx] = (bf16_t)t[tx][ty + i];
}

// ------- per-head V transpose: qkv[s][2*HID + h*HD + d] -> vt[(h*HD+d)*S + s] -------
__global__ void vtrans(const bf16_t* __restrict__ qkv, bf16_t* __restrict__ vt) {
  __shared__ bf16_t t[32][33];
  int h = blockIdx.z;
  int s0 = blockIdx.x * 32, d0 = blockIdx.y * 32;
  int tx = threadIdx.x, ty = threadIdx.y;  // 32 x 8
#pragma unroll
  for (int i = 0; i < 32; i += 8)
    t[ty + i][tx] = qkv[(size_t)(s0 + ty + i) * N3 + 2 * HID + h * HD + d0 + tx];
  __syncthreads();
#pragma unroll
  for (int i = 0; i < 32; i += 8)
    vt[(size_t)(h * HD + d0 + ty + i) * S_ + s0 + tx] = t[tx][ty + i];
}

// ================= 256x256 8-phase GEMM (T2+T3+T4+T5) =================
// C[M][N] = A[M][K] * BT[N][K]^T + bias.  512 thr (8 waves, 2Mx4N),
// K-tile=32, 4-slot LDS ring (4x32KB=128KB), stage tile t+3 while computing t,
// vmcnt(8) once per tile (2 K-tiles = 8 loads in flight), st_16x32-style
// XOR swizzle (byte ^= ((byte>>9)&1)<<5) applied as: linear LDS dest +
// inverse-swizzled per-lane GLOBAL source + swizzled ds_read offset.

template <bool STG, int VMC>
__device__ __forceinline__ void tile_step(
    char* __restrict__ smem, int slotbase, int aoff, int boff,
    const bf16_t* gA, const bf16_t* gB, int kst, size_t sk128,
    char* stg_dst, f32x4 (&acc)[8][4]) {
  const char* ab = smem + slotbase;
  const char* bb = smem + slotbase + 16384;
  bf16x8 a[4], b[4];
  // ---- phase A: 8 ds_read_b128, stage A-halves of tile t+3, 16 MFMA ----
#pragma unroll
  for (int ni = 0; ni < 4; ++ni) b[ni] = *(const bf16x8*)(bb + boff + ni * 1024);
#pragma unroll
  for (int mi = 0; mi < 4; ++mi) a[mi] = *(const bf16x8*)(ab + aoff + mi * 1024);
  if constexpr (STG) {
    __builtin_amdgcn_global_load_lds((const AS1 void*)(gA + kst), (AS3 void*)(stg_dst), 16, 0, 0);
    __builtin_amdgcn_global_load_lds((const AS1 void*)(gA + sk128 + kst), (AS3 void*)(stg_dst + 8192), 16, 0, 0);
  }
  __builtin_amdgcn_s_barrier();
  __builtin_amdgcn_s_setprio(1);
#pragma unroll
  for (int mi = 0; mi < 4; ++mi)
#pragma unroll
    for (int ni = 0; ni < 4; ++ni)
      acc[mi][ni] = __builtin_amdgcn_mfma_f32_16x16x32_bf16(a[mi], b[ni], acc[mi][ni], 0, 0, 0);
  __builtin_amdgcn_s_setprio(0);
  __builtin_amdgcn_s_barrier();
  // ---- phase B: 4 ds_read_b128, stage B-halves, counted vmcnt, 16 MFMA ----
#pragma unroll
  for (int mi = 0; mi < 4; ++mi) a[mi] = *(const bf16x8*)(ab + aoff + (4 + mi) * 1024);
  if constexpr (STG) {
    __builtin_amdgcn_global_load_lds((const AS1 void*)(gB + kst), (AS3 void*)(stg_dst + 16384), 16, 0, 0);
    __builtin_amdgcn_global_load_lds((const AS1 void*)(gB + sk128 + kst), (AS3 void*)(stg_dst + 24576), 16, 0, 0);
  }
  if constexpr (VMC == 8)      asm volatile("s_waitcnt vmcnt(8)" ::: "memory");
  else if constexpr (VMC == 4) asm volatile("s_waitcnt vmcnt(4)" ::: "memory");
  else if constexpr (VMC == 0) asm volatile("s_waitcnt vmcnt(0)" ::: "memory");
  __builtin_amdgcn_s_barrier();
  __builtin_amdgcn_s_setprio(1);
#pragma unroll
  for (int mi = 0; mi < 4; ++mi)
#pragma unroll
    for (int ni = 0; ni < 4; ++ni)
      acc[4 + mi][ni] = __builtin_amdgcn_mfma_f32_16x16x32_bf16(a[mi], b[ni], acc[4 + mi][ni], 0, 0, 0);
  __builtin_amdgcn_s_setprio(0);
  __builtin_amdgcn_s_barrier();
}

template <typename OutT>
__global__ __launch_bounds__(512, 2) void gemm256(
    const bf16_t* __restrict__ A, const bf16_t* __restrict__ BT,
    const float* __restrict__ bias, OutT* __restrict__ C,
    int M, int N, int K) {
  extern __shared__ char smem[];
  const int tid = threadIdx.x;
  const int wv = tid >> 6, ln = tid & 63;
  const int lr = ln & 15, lg = ln >> 4;
  const int wm = wv >> 2, wn = wv & 3;

  const int nx = N >> 8;
  const int qx = gridDim.x >> 3;
  const int wg = (blockIdx.x & 7) * qx + (blockIdx.x >> 3);  // XCD-contiguous
  const int m0 = (wg / nx) * 256, n0 = (wg % nx) * 256;

  // staging: per-lane inverse-swizzled global source; linear LDS dest.
  // LDS byte p = r*8192 + wv*1024 + ln*16 holds logical q = p ^ (((p>>9)&1)<<5):
  //   row = r*128 + wv*16 + (ln>>2), col = ((ln&3)<<3) ^ ((ln&32)>>1)
  const int lrow = wv * 16 + (ln >> 2);
  const int lcol = ((ln & 3) << 3) ^ ((ln & 32) >> 1);
  const bf16_t* gA = A + (size_t)(m0 + lrow) * K + lcol;
  const bf16_t* gB = BT + (size_t)(n0 + lrow) * K + lcol;
  const size_t sk128 = (size_t)128 * K;
  char* stg_wbase = smem + wv * 1024;

  // swizzled frag-read offsets: byte = row*64 + lg*16, ^32 when row&8 (=lr&8)
  const int sw = (lr & 8) << 2;
  const int aoff = (wm * 128 + lr) * 64 + ((lg * 16) ^ sw);
  const int boff = (wn * 64 + lr) * 64 + ((lg * 16) ^ sw);

  f32x4 acc[8][4] = {};

  // prologue: stage tiles 0,1,2 (12 loads/wave); wait tile0 (oldest 4)
#pragma unroll
  for (int t = 0; t < 3; ++t) {
    char* d = stg_wbase + t * 32768;
    __builtin_amdgcn_global_load_lds((const AS1 void*)(gA + t * 32), (AS3 void*)(d), 16, 0, 0);
    __builtin_amdgcn_global_load_lds((const AS1 void*)(gA + sk128 + t * 32), (AS3 void*)(d + 8192), 16, 0, 0);
    __builtin_amdgcn_global_load_lds((const AS1 void*)(gB + t * 32), (AS3 void*)(d + 16384), 16, 0, 0);
    __builtin_amdgcn_global_load_lds((const AS1 void*)(gB + sk128 + t * 32), (AS3 void*)(d + 24576), 16, 0, 0);
  }
  asm volatile("s_waitcnt vmcnt(8)" ::: "memory");
  __builtin_amdgcn_s_barrier();

  const int NT = K >> 5;  // 128
  int t = 0;
  for (; t < NT - 3; ++t)
    tile_step<true, 8>(smem, (t & 3) * 32768, aoff, boff, gA, gB, (t + 3) * 32,
                       sk128, stg_wbase + ((t + 3) & 3) * 32768, acc);
  tile_step<false, 4>(smem, (t & 3) * 32768, aoff, boff, gA, gB, 0, sk128, smem, acc); ++t;
  tile_step<false, 0>(smem, (t & 3) * 32768, aoff, boff, gA, gB, 0, sk128, smem, acc); ++t;
  tile_step<false, -1>(smem, (t & 3) * 32768, aoff, boff, gA, gB, 0, sk128, smem, acc);

  // epilogue
#pragma unroll
  for (int mi = 0; mi < 8; ++mi)
#pragma unroll
    for (int ni = 0; ni < 4; ++ni) {
      const int col = n0 + wn * 64 + ni * 16 + lr;
      const float bv = bias[col];
#pragma unroll
      for (int i = 0; i < 4; ++i) {
        const int row = m0 + wm * 128 + mi * 16 + lg * 4 + i;
        C[(size_t)row * N + col] = (OutT)(acc[mi][ni][i] + bv);
      }
    }
}

// ---------------- flash attention: causal, 32 heads, d=128 ----------------
// block = (q-tile of 64 rows, head); 4 waves x 16 rows each; KV tile = 64
// LDS: Ks (17.4KB, P overlaid after QK barrier) + Vts (18.4KB) = 35.8KB -> 4 blocks/CU
__global__ __launch_bounds__(256, 4) void attn_fwd(
    const bf16_t* __restrict__ qkv, const bf16_t* __restrict__ vt,
    bf16_t* __restrict__ ctx) {
  __shared__ __align__(16) bf16_t Ks[64][136];    // K rows (kv), 272B stride
  __shared__ __align__(16) bf16_t Vts[128][72];   // V^T rows (d), 144B stride

  const int tid = threadIdx.x;
  const int wv = tid >> 6, ln = tid & 63;
  // P buffer overlaid on Ks: per-wave [16][72] slice (4*2304B = 9216B <= 17408B)
  bf16_t* Pl = &Ks[0][0] + wv * (16 * 72);

  // block decode: XCD-clustered heads + balanced causal work.
  const int bid = blockIdx.x;
  const int h  = ((bid & 7) << 2) + (bid >> 8);
  const int qt = 31 - ((((bid >> 3) & 31) + ((bid >> 8) << 3)) & 31);
  const int q0 = qt * 64;
  const int lr = ln & 15, lg = ln >> 4;

  // Q fragments with softmax scale folded in
  bf16x8 qf[4];
#pragma unroll
  for (int kk = 0; kk < 4; ++kk) {
    bf16x8 r = *(const bf16x8*)(qkv + (size_t)(q0 + 16 * wv + lr) * N3 + h * HD + kk * 32 + lg * 8);
#pragma unroll
    for (int j = 0; j < 8; ++j) r[j] = (bf16_t)((float)r[j] * SCALE);
    qf[kk] = r;
  }

  f32x4 oacc[8] = {};
  float mrow[4], psum[4];
#pragma unroll
  for (int i = 0; i < 4; ++i) { mrow[i] = -INFINITY; psum[i] = 0.f; }

  const int ntiles = qt + 1;
  for (int t = 0; t < ntiles; ++t) {
    const int kv0 = t * 64;
    __syncthreads();
#pragma unroll
    for (int it = 0; it < 4; ++it) {
      int c = tid + it * 256;
      {
        int row = c >> 4, col = (c & 15) * 8;
        *(bf16x8*)&Ks[row][col] =
            *(const bf16x8*)(qkv + (size_t)(kv0 + row) * N3 + HID + h * HD + col);
      }
      {
        int row = c >> 3, col = (c & 7) * 8;
        *(bf16x8*)&Vts[row][col] =
            *(const bf16x8*)(vt + (size_t)(h * HD + row) * S_ + kv0 + col);
      }
    }
    __syncthreads();

    // S = Q K^T
    f32x4 sacc[4] = {};
#pragma unroll
    for (int kk = 0; kk < 4; ++kk)
#pragma unroll
      for (int ni = 0; ni < 4; ++ni) {
        bf16x8 kf = *(const bf16x8*)&Ks[16 * ni + lr][kk * 32 + lg * 8];
        sacc[ni] = __builtin_amdgcn_mfma_f32_16x16x32_bf16(qf[kk], kf, sacc[ni], 0, 0, 0);
      }

    const bool needmask = (kv0 + 63 > q0 + 16 * wv);
    float p[4][4];
    float mx[4];
    bool grow = false;
#pragma unroll
    for (int i = 0; i < 4; ++i) {
      const int row = q0 + 16 * wv + lg * 4 + i;
      float m_ = -INFINITY;
#pragma unroll
      for (int ni = 0; ni < 4; ++ni) {
        float s = sacc[ni][i];
        if (needmask && (kv0 + 16 * ni + lr > row)) s = -INFINITY;
        p[ni][i] = s;
        m_ = fmaxf(m_, s);
      }
      m_ = fmaxf(m_, __shfl_xor(m_, 1, 64));
      m_ = fmaxf(m_, __shfl_xor(m_, 2, 64));
      m_ = fmaxf(m_, __shfl_xor(m_, 4, 64));
      m_ = fmaxf(m_, __shfl_xor(m_, 8, 64));
      mx[i] = m_;
      grow |= (m_ > mrow[i]);
    }
    if (__any(grow)) {
      float alpha[4];
#pragma unroll
      for (int i = 0; i < 4; ++i) {
        const float mn = fmaxf(mrow[i], mx[i]);
        alpha[i] = __expf(mrow[i] - mn);
        mrow[i] = mn;
        psum[i] *= alpha[i];
      }
#pragma unroll
      for (int nf = 0; nf < 8; ++nf)
#pragma unroll
        for (int i = 0; i < 4; ++i) oacc[nf][i] *= alpha[i];
    }
#pragma unroll
    for (int i = 0; i < 4; ++i) {
      float ps = 0.f;
#pragma unroll
      for (int ni = 0; ni < 4; ++ni) {
        float e = __expf(p[ni][i] - mrow[i]);
        p[ni][i] = e;
        ps += e;
      }
      psum[i] += ps;
    }

    __syncthreads();

#pragma unroll
    for (int ni = 0; ni < 4; ++ni)
#pragma unroll
      for (int i = 0; i < 4; ++i)
        Pl[(lg * 4 + i) * 72 + 16 * ni + lr] = (bf16_t)p[ni][i];

#pragma unroll
    for (int kk2 = 0; kk2 < 2; ++kk2) {
      bf16x8 pf = *(const bf16x8*)&Pl[lr * 72 + kk2 * 32 + lg * 8];
#pragma unroll
      for (int nf = 0; nf < 8; ++nf) {
        bf16x8 vf = *(const bf16x8*)&Vts[16 * nf + lr][kk2 * 32 + lg * 8];
        oacc[nf] = __builtin_amdgcn_mfma_f32_16x16x32_bf16(pf, vf, oacc[nf], 0, 0, 0);
      }
    }
  }

#pragma unroll
  for (int i = 0; i < 4; ++i) {
    float s = psum[i];
    s += __shfl_xor(s, 1, 64);
    s += __shfl_xor(s, 2, 64);
    s += __shfl_xor(s, 4, 64);
    s += __shfl_xor(s, 8, 64);
    psum[i] = 1.f / s;
  }
#pragma unroll
  for (int nf = 0; nf < 8; ++nf)
#pragma unroll
    for (int i = 0; i < 4; ++i) {
      int row = q0 + 16 * wv + lg * 4 + i;
      int col = h * HD + 16 * nf + lr;
      ctx[(size_t)row * HID + col] = (bf16_t)(oacc[nf][i] * psum[i]);
    }
}

// ---------------- launcher ----------------
extern "C" void kernel_launch(void* const* d_in, const int* in_sizes, int n_in,
                              void* d_out, int out_size, void* d_ws, size_t ws_size,
                              hipStream_t stream) {
  const float* x    = (const float*)d_in[0];
  const float* wqkv = (const float*)d_in[1];
  const float* bqkv = (const float*)d_in[2];
  const float* ow   = (const float*)d_in[3];
  const float* ob   = (const float*)d_in[4];
  float* out = (float*)d_out;

  char* w = (char*)d_ws;
  bf16_t* xb    = (bf16_t*)(w);                          // S*HID       bf16 (16 MB)
  bf16_t* wqkvT = (bf16_t*)(w + (size_t)16777216);       // N3*HID      bf16 (100.7 MB)
  bf16_t* qkv   = (bf16_t*)(w + (size_t)117440512);      // S*N3        bf16 (50.3 MB)
  bf16_t* vt    = (bf16_t*)(w + (size_t)167772160);      // NH*HD*S     bf16 (16 MB)
  bf16_t* ctx   = (bf16_t*)(w + (size_t)184549376);      // S*HID       bf16 (16 MB)
  bf16_t* owT   = (bf16_t*)(w + (size_t)201326592);      // HID*HID     bf16 (33.6 MB)

  (void)in_sizes; (void)n_in; (void)out_size; (void)ws_size;

  cvt_f32_bf16<<<(S_ * HID / 4 + 255) / 256, 256, 0, stream>>>(x, xb, S_ * HID / 4);
  transcvt<<<dim3(N3 / 32, HID / 32), dim3(32, 8), 0, stream>>>(wqkv, wqkvT, HID, N3);
  transcvt<<<dim3(HID / 32, HID / 32), dim3(32, 8), 0, stream>>>(ow, owT, HID, HID);
  // QKV projection: 256^2 8-phase, grid 8x48=384 (%8==0), 128KB dynamic LDS
  gemm256<bf16_t><<<(S_ / 256) * (N3 / 256), 512, 131072, stream>>>(xb, wqkvT, bqkv, qkv, S_, N3, HID);
  vtrans<<<dim3(S_ / 32, HD / 32, NH), dim3(32, 8), 0, stream>>>(qkv, vt);
  attn_fwd<<<(S_ / 64) * NH, 256, 0, stream>>>(qkv, vt, ctx);
  // out projection: grid 8x16=128 (%8==0)
  gemm256<float><<<(S_ / 256) * (HID / 256), 512, 131072, stream>>>(ctx, owT, ob, out, S_, HID, HID);
}

// Round 4
// 550.598 us; speedup vs baseline: 1.4121x; 1.0626x over previous
//
#include <hip/hip_runtime.h>
#include <hip/hip_bf16.h>
#include <math.h>

typedef __bf16 bf16_t;
typedef __bf16 bf16x8 __attribute__((ext_vector_type(8)));
typedef float f32x4 __attribute__((ext_vector_type(4)));

#define AS1 __attribute__((address_space(1)))
#define AS3 __attribute__((address_space(3)))

static constexpr int S_  = 2048;
static constexpr int HID = 4096;
static constexpr int NH  = 32;
static constexpr int HD  = 128;
static constexpr int N3  = 3 * HID;           // 12288
static constexpr float SCALE = 0.08838834764831845f;  // 1/sqrt(128)

// ---------------- fp32 -> bf16 convert (vectorized) ----------------
__global__ void cvt_f32_bf16(const float* __restrict__ in, bf16_t* __restrict__ out, int n4) {
  int i = blockIdx.x * blockDim.x + threadIdx.x;
  if (i >= n4) return;
  float4 v = ((const float4*)in)[i];
  union { bf16_t h[4]; short4 s4; } u;
  u.h[0] = (bf16_t)v.x; u.h[1] = (bf16_t)v.y; u.h[2] = (bf16_t)v.z; u.h[3] = (bf16_t)v.w;
  ((short4*)out)[i] = u.s4;
}

// ------------- transpose + convert: in[R][C] f32 -> out[C][R] bf16 -------------
__global__ void transcvt(const float* __restrict__ in, bf16_t* __restrict__ out, int R, int C) {
  __shared__ float t[32][33];
  int r0 = blockIdx.y * 32, c0 = blockIdx.x * 32;
  int tx = threadIdx.x, ty = threadIdx.y;  // 32 x 8
#pragma unroll
  for (int i = 0; i < 32; i += 8)
    t[ty + i][tx] = in[(size_t)(r0 + ty + i) * C + c0 + tx];
  __syncthreads();
#pragma unroll
  for (int i = 0; i < 32; i += 8)
    out[(size_t)(c0 + ty + i) * R + r0 + tx] = (bf16_t)t[tx][ty + i];
}

// ------- per-head V transpose: qkv[s][2*HID + h*HD + d] -> vt[(h*HD+d)*S + s] -------
__global__ void vtrans(const bf16_t* __restrict__ qkv, bf16_t* __restrict__ vt) {
  __shared__ bf16_t t[32][33];
  int h = blockIdx.z;
  int s0 = blockIdx.x * 32, d0 = blockIdx.y * 32;
  int tx = threadIdx.x, ty = threadIdx.y;  // 32 x 8
#pragma unroll
  for (int i = 0; i < 32; i += 8)
    t[ty + i][tx] = qkv[(size_t)(s0 + ty + i) * N3 + 2 * HID + h * HD + d0 + tx];
  __syncthreads();
#pragma unroll
  for (int i = 0; i < 32; i += 8)
    vt[(size_t)(h * HD + d0 + ty + i) * S_ + s0 + tx] = t[tx][ty + i];
}

// ============ 256x128-tile GEMM, 3-slot ring, 2 blocks/CU (T1+T2+T4+T5) ============
// C[M][N] = A[M][K] * BT[N][K]^T + bias.  512 thr = 8 waves (4M x 2N), wave = 64x64.
// Slot = 24KB ([A 256x32: 16KB][B 128x32: 8KB]); 3 slots = 72KB -> 2 blocks/CU.
// Stage tile t+2 while computing t; vmcnt(3) waits only loads issued a full tile ago.
// st_16x32 swizzle: linear LDS dest + inverse-swizzled global source + swizzled read.

template <bool STG, int VMC>
__device__ __forceinline__ void tile_step(
    const char* slot, int aoff, int boff,
    const bf16_t* gA, const bf16_t* gB, int kst, size_t skA,
    char* stg_dst, f32x4 (&acc)[4][4]) {
  bf16x8 a[4], b[4];
#pragma unroll
  for (int mi = 0; mi < 4; ++mi) a[mi] = *(const bf16x8*)(slot + aoff + mi * 1024);
#pragma unroll
  for (int ni = 0; ni < 4; ++ni) b[ni] = *(const bf16x8*)(slot + 16384 + boff + ni * 1024);
  if constexpr (STG) {
    __builtin_amdgcn_global_load_lds((const AS1 void*)(gA + kst), (AS3 void*)(stg_dst), 16, 0, 0);
    __builtin_amdgcn_global_load_lds((const AS1 void*)(gA + skA + kst), (AS3 void*)(stg_dst + 8192), 16, 0, 0);
    __builtin_amdgcn_global_load_lds((const AS1 void*)(gB + kst), (AS3 void*)(stg_dst + 16384), 16, 0, 0);
  }
  if constexpr (VMC == 3) asm volatile("s_waitcnt vmcnt(3)" ::: "memory");
  else if constexpr (VMC == 0) asm volatile("s_waitcnt vmcnt(0)" ::: "memory");
  __builtin_amdgcn_s_barrier();
  __builtin_amdgcn_s_setprio(1);
#pragma unroll
  for (int mi = 0; mi < 4; ++mi)
#pragma unroll
    for (int ni = 0; ni < 4; ++ni)
      acc[mi][ni] = __builtin_amdgcn_mfma_f32_16x16x32_bf16(a[mi], b[ni], acc[mi][ni], 0, 0, 0);
  __builtin_amdgcn_s_setprio(0);
  __builtin_amdgcn_s_barrier();
}

template <typename OutT>
__global__ __launch_bounds__(512, 4) void gemm_p(
    const bf16_t* __restrict__ A, const bf16_t* __restrict__ BT,
    const float* __restrict__ bias, OutT* __restrict__ C,
    int M, int N, int K) {
  extern __shared__ char smem[];
  const int tid = threadIdx.x;
  const int wv = tid >> 6, ln = tid & 63;
  const int lr = ln & 15, lg = ln >> 4;
  const int wm = wv >> 1, wn = wv & 1;

  const int nx = N >> 7;
  const int qx = gridDim.x >> 3;
  const int wg = (blockIdx.x & 7) * qx + (blockIdx.x >> 3);  // XCD-contiguous
  const int m0 = (wg / nx) * 256, n0 = (wg % nx) * 128;

  // staging: linear LDS dest; per-lane inverse-swizzled global source.
  // LDS byte p (in 8KB region) = wv*1024 + ln*16 -> row = wv*16 + (ln>>2),
  // logical col elems = ((ln&3)<<3) ^ (16 if row&8 i.e. ln&32)
  const int lrow = wv * 16 + (ln >> 2);
  const int lcol = ((ln & 3) << 3) ^ ((ln & 32) >> 1);
  const bf16_t* gA = A + (size_t)(m0 + lrow) * K + lcol;
  const bf16_t* gB = BT + (size_t)(n0 + lrow) * K + lcol;
  const size_t skA = (size_t)128 * K;

  // swizzled frag-read offsets: byte = row*64 + (lg*16 ^ (32 if row&8(=lr&8)))
  const int sw = (lr & 8) << 2;
  const int aoff = (wm * 64 + lr) * 64 + ((lg * 16) ^ sw);
  const int boff = (wn * 64 + lr) * 64 + ((lg * 16) ^ sw);

  f32x4 acc[4][4] = {};

  // prologue: stage tiles 0,1 (6 loads/wave); wait tile0 (oldest 3)
#pragma unroll
  for (int t = 0; t < 2; ++t) {
    char* d = smem + t * 24576 + wv * 1024;
    __builtin_amdgcn_global_load_lds((const AS1 void*)(gA + t * 32), (AS3 void*)(d), 16, 0, 0);
    __builtin_amdgcn_global_load_lds((const AS1 void*)(gA + skA + t * 32), (AS3 void*)(d + 8192), 16, 0, 0);
    __builtin_amdgcn_global_load_lds((const AS1 void*)(gB + t * 32), (AS3 void*)(d + 16384), 16, 0, 0);
  }
  asm volatile("s_waitcnt vmcnt(3)" ::: "memory");
  __builtin_amdgcn_s_barrier();

  const int NT = K >> 5;  // 128
  int slot = 0, nslot = 2;  // compute slot t%3; stage dest (t+2)%3
  int t = 0;
  for (; t < NT - 2; ++t) {
    tile_step<true, 3>(smem + slot * 24576, aoff, boff, gA, gB, (t + 2) * 32,
                       skA, smem + nslot * 24576 + wv * 1024, acc);
    slot = (slot == 2) ? 0 : slot + 1;
    nslot = (nslot == 2) ? 0 : nslot + 1;
  }
  tile_step<false, 0>(smem + slot * 24576, aoff, boff, gA, gB, 0, skA, smem, acc);
  slot = (slot == 2) ? 0 : slot + 1;
  tile_step<false, -1>(smem + slot * 24576, aoff, boff, gA, gB, 0, skA, smem, acc);

  // epilogue
#pragma unroll
  for (int mi = 0; mi < 4; ++mi)
#pragma unroll
    for (int ni = 0; ni < 4; ++ni) {
      const int col = n0 + wn * 64 + ni * 16 + lr;
      const float bv = bias[col];
#pragma unroll
      for (int i = 0; i < 4; ++i) {
        const int row = m0 + wm * 64 + mi * 16 + lg * 4 + i;
        C[(size_t)row * N + col] = (OutT)(acc[mi][ni][i] + bv);
      }
    }
}

// ---------------- flash attention: causal, 32 heads, d=128 ----------------
// block = (q-tile of 64 rows, head); 4 waves x 16 rows each; KV tile = 64
// LDS: Ks (17.4KB, P overlaid after QK barrier) + Vts (18.4KB) = 35.8KB -> 4 blocks/CU
__global__ __launch_bounds__(256, 4) void attn_fwd(
    const bf16_t* __restrict__ qkv, const bf16_t* __restrict__ vt,
    bf16_t* __restrict__ ctx) {
  __shared__ __align__(16) bf16_t Ks[64][136];    // K rows (kv), 272B stride
  __shared__ __align__(16) bf16_t Vts[128][72];   // V^T rows (d), 144B stride

  const int tid = threadIdx.x;
  const int wv = tid >> 6, ln = tid & 63;
  // P buffer overlaid on Ks: per-wave [16][72] slice (4*2304B = 9216B <= 17408B)
  bf16_t* Pl = &Ks[0][0] + wv * (16 * 72);

  // block decode: XCD-clustered heads + balanced causal work.
  const int bid = blockIdx.x;
  const int h  = ((bid & 7) << 2) + (bid >> 8);
  const int qt = 31 - ((((bid >> 3) & 31) + ((bid >> 8) << 3)) & 31);
  const int q0 = qt * 64;
  const int lr = ln & 15, lg = ln >> 4;

  // Q fragments with softmax scale folded in
  bf16x8 qf[4];
#pragma unroll
  for (int kk = 0; kk < 4; ++kk) {
    bf16x8 r = *(const bf16x8*)(qkv + (size_t)(q0 + 16 * wv + lr) * N3 + h * HD + kk * 32 + lg * 8);
#pragma unroll
    for (int j = 0; j < 8; ++j) r[j] = (bf16_t)((float)r[j] * SCALE);
    qf[kk] = r;
  }

  f32x4 oacc[8] = {};
  float mrow[4], psum[4];
#pragma unroll
  for (int i = 0; i < 4; ++i) { mrow[i] = -INFINITY; psum[i] = 0.f; }

  const int ntiles = qt + 1;
  for (int t = 0; t < ntiles; ++t) {
    const int kv0 = t * 64;
    __syncthreads();
#pragma unroll
    for (int it = 0; it < 4; ++it) {
      int c = tid + it * 256;
      {
        int row = c >> 4, col = (c & 15) * 8;
        *(bf16x8*)&Ks[row][col] =
            *(const bf16x8*)(qkv + (size_t)(kv0 + row) * N3 + HID + h * HD + col);
      }
      {
        int row = c >> 3, col = (c & 7) * 8;
        *(bf16x8*)&Vts[row][col] =
            *(const bf16x8*)(vt + (size_t)(h * HD + row) * S_ + kv0 + col);
      }
    }
    __syncthreads();

    // S = Q K^T
    f32x4 sacc[4] = {};
#pragma unroll
    for (int kk = 0; kk < 4; ++kk)
#pragma unroll
      for (int ni = 0; ni < 4; ++ni) {
        bf16x8 kf = *(const bf16x8*)&Ks[16 * ni + lr][kk * 32 + lg * 8];
        sacc[ni] = __builtin_amdgcn_mfma_f32_16x16x32_bf16(qf[kk], kf, sacc[ni], 0, 0, 0);
      }

    const bool needmask = (kv0 + 63 > q0 + 16 * wv);
    float p[4][4];
    float mx[4];
    bool grow = false;
#pragma unroll
    for (int i = 0; i < 4; ++i) {
      const int row = q0 + 16 * wv + lg * 4 + i;
      float m_ = -INFINITY;
#pragma unroll
      for (int ni = 0; ni < 4; ++ni) {
        float s = sacc[ni][i];
        if (needmask && (kv0 + 16 * ni + lr > row)) s = -INFINITY;
        p[ni][i] = s;
        m_ = fmaxf(m_, s);
      }
      m_ = fmaxf(m_, __shfl_xor(m_, 1, 64));
      m_ = fmaxf(m_, __shfl_xor(m_, 2, 64));
      m_ = fmaxf(m_, __shfl_xor(m_, 4, 64));
      m_ = fmaxf(m_, __shfl_xor(m_, 8, 64));
      mx[i] = m_;
      grow |= (m_ > mrow[i]);
    }
    if (__any(grow)) {
      float alpha[4];
#pragma unroll
      for (int i = 0; i < 4; ++i) {
        const float mn = fmaxf(mrow[i], mx[i]);
        alpha[i] = __expf(mrow[i] - mn);
        mrow[i] = mn;
        psum[i] *= alpha[i];
      }
#pragma unroll
      for (int nf = 0; nf < 8; ++nf)
#pragma unroll
        for (int i = 0; i < 4; ++i) oacc[nf][i] *= alpha[i];
    }
#pragma unroll
    for (int i = 0; i < 4; ++i) {
      float ps = 0.f;
#pragma unroll
      for (int ni = 0; ni < 4; ++ni) {
        float e = __expf(p[ni][i] - mrow[i]);
        p[ni][i] = e;
        ps += e;
      }
      psum[i] += ps;
    }

    __syncthreads();

#pragma unroll
    for (int ni = 0; ni < 4; ++ni)
#pragma unroll
      for (int i = 0; i < 4; ++i)
        Pl[(lg * 4 + i) * 72 + 16 * ni + lr] = (bf16_t)p[ni][i];

#pragma unroll
    for (int kk2 = 0; kk2 < 2; ++kk2) {
      bf16x8 pf = *(const bf16x8*)&Pl[lr * 72 + kk2 * 32 + lg * 8];
#pragma unroll
      for (int nf = 0; nf < 8; ++nf) {
        bf16x8 vf = *(const bf16x8*)&Vts[16 * nf + lr][kk2 * 32 + lg * 8];
        oacc[nf] = __builtin_amdgcn_mfma_f32_16x16x32_bf16(pf, vf, oacc[nf], 0, 0, 0);
      }
    }
  }

#pragma unroll
  for (int i = 0; i < 4; ++i) {
    float s = psum[i];
    s += __shfl_xor(s, 1, 64);
    s += __shfl_xor(s, 2, 64);
    s += __shfl_xor(s, 4, 64);
    s += __shfl_xor(s, 8, 64);
    psum[i] = 1.f / s;
  }
#pragma unroll
  for (int nf = 0; nf < 8; ++nf)
#pragma unroll
    for (int i = 0; i < 4; ++i) {
      int row = q0 + 16 * wv + lg * 4 + i;
      int col = h * HD + 16 * nf + lr;
      ctx[(size_t)row * HID + col] = (bf16_t)(oacc[nf][i] * psum[i]);
    }
}

// ---------------- launcher ----------------
extern "C" void kernel_launch(void* const* d_in, const int* in_sizes, int n_in,
                              void* d_out, int out_size, void* d_ws, size_t ws_size,
                              hipStream_t stream) {
  const float* x    = (const float*)d_in[0];
  const float* wqkv = (const float*)d_in[1];
  const float* bqkv = (const float*)d_in[2];
  const float* ow   = (const float*)d_in[3];
  const float* ob   = (const float*)d_in[4];
  float* out = (float*)d_out;

  char* w = (char*)d_ws;
  bf16_t* xb    = (bf16_t*)(w);                          // S*HID       bf16 (16 MB)
  bf16_t* wqkvT = (bf16_t*)(w + (size_t)16777216);       // N3*HID      bf16 (100.7 MB)
  bf16_t* qkv   = (bf16_t*)(w + (size_t)117440512);      // S*N3        bf16 (50.3 MB)
  bf16_t* vt    = (bf16_t*)(w + (size_t)167772160);      // NH*HD*S     bf16 (16 MB)
  bf16_t* ctx   = (bf16_t*)(w + (size_t)184549376);      // S*HID       bf16 (16 MB)
  bf16_t* owT   = (bf16_t*)(w + (size_t)201326592);      // HID*HID     bf16 (33.6 MB)

  (void)in_sizes; (void)n_in; (void)out_size; (void)ws_size;

  cvt_f32_bf16<<<(S_ * HID / 4 + 255) / 256, 256, 0, stream>>>(x, xb, S_ * HID / 4);
  transcvt<<<dim3(N3 / 32, HID / 32), dim3(32, 8), 0, stream>>>(wqkv, wqkvT, HID, N3);
  transcvt<<<dim3(HID / 32, HID / 32), dim3(32, 8), 0, stream>>>(ow, owT, HID, HID);
  // QKV projection: grid 8*96=768 (3 exact rounds at 2 blocks/CU), 72KB dynamic LDS
  gemm_p<bf16_t><<<(S_ / 256) * (N3 / 128), 512, 73728, stream>>>(xb, wqkvT, bqkv, qkv, S_, N3, HID);
  vtrans<<<dim3(S_ / 32, HD / 32, NH), dim3(32, 8), 0, stream>>>(qkv, vt);
  attn_fwd<<<(S_ / 64) * NH, 256, 0, stream>>>(qkv, vt, ctx);
  // out projection: grid 8*32=256 (1 exact round)
  gemm_p<float><<<(S_ / 256) * (HID / 128), 512, 73728, stream>>>(ctx, owT, ob, out, S_, HID, HID);
}

// Round 6
// 520.332 us; speedup vs baseline: 1.4943x; 1.0582x over previous
//
#include <hip/hip_runtime.h>
#include <hip/hip_bf16.h>
#include <math.h>

typedef __bf16 bf16_t;
typedef __bf16 bf16x8 __attribute__((ext_vector_type(8)));
typedef float f32x4 __attribute__((ext_vector_type(4)));

#define AS1 __attribute__((address_space(1)))
#define AS3 __attribute__((address_space(3)))

static constexpr int S_  = 2048;
static constexpr int HID = 4096;
static constexpr int NH  = 32;
static constexpr int HD  = 128;
static constexpr int N3  = 3 * HID;           // 12288
static constexpr float SCALE = 0.08838834764831845f;  // 1/sqrt(128)

// ---------------- fp32 -> bf16 convert (vectorized) ----------------
__global__ void cvt_f32_bf16(const float* __restrict__ in, bf16_t* __restrict__ out, int n4) {
  int i = blockIdx.x * blockDim.x + threadIdx.x;
  if (i >= n4) return;
  float4 v = ((const float4*)in)[i];
  union { bf16_t h[4]; short4 s4; } u;
  u.h[0] = (bf16_t)v.x; u.h[1] = (bf16_t)v.y; u.h[2] = (bf16_t)v.z; u.h[3] = (bf16_t)v.w;
  ((short4*)out)[i] = u.s4;
}

// ------- transpose + convert: in[R][C] f32 -> out[C][R] bf16, 64x64 tile -------
// 256 thr. Loads: float4/lane; stores: bf16x8/lane (16B, coalesced 128B/row-group).
__global__ __launch_bounds__(256) void transcvt64(
    const float* __restrict__ in, bf16_t* __restrict__ out, int R, int C) {
  __shared__ float t[64][65];
  const int r0 = blockIdx.y * 64, c0 = blockIdx.x * 64;
  const int tid = threadIdx.x;
  const int rr = tid >> 4, c4 = (tid & 15) * 4;   // 16 rows/iter x 16 float4
#pragma unroll
  for (int it = 0; it < 4; ++it) {
    float4 v = *(const float4*)&in[(size_t)(r0 + rr + it * 16) * C + c0 + c4];
    t[rr + it * 16][c4 + 0] = v.x;
    t[rr + it * 16][c4 + 1] = v.y;
    t[rr + it * 16][c4 + 2] = v.z;
    t[rr + it * 16][c4 + 3] = v.w;
  }
  __syncthreads();
  const int cc = tid >> 3, r8 = (tid & 7) * 8;    // 32 out-rows/iter x 8 chunks
#pragma unroll
  for (int it = 0; it < 2; ++it) {
    const int c = cc + it * 32;
    bf16x8 w;
#pragma unroll
    for (int j = 0; j < 8; ++j) w[j] = (bf16_t)t[r8 + j][c];
    *(bf16x8*)&out[(size_t)(c0 + c) * R + r0 + r8] = w;
  }
}

// ------- per-head V transpose: qkv[s][2*HID + h*HD + d] -> vt[(h*HD+d)*S + s] -------
__global__ void vtrans(const bf16_t* __restrict__ qkv, bf16_t* __restrict__ vt) {
  __shared__ bf16_t t[32][33];
  int h = blockIdx.z;
  int s0 = blockIdx.x * 32, d0 = blockIdx.y * 32;
  int tx = threadIdx.x, ty = threadIdx.y;  // 32 x 8
#pragma unroll
  for (int i = 0; i < 32; i += 8)
    t[ty + i][tx] = qkv[(size_t)(s0 + ty + i) * N3 + 2 * HID + h * HD + d0 + tx];
  __syncthreads();
#pragma unroll
  for (int i = 0; i < 32; i += 8)
    vt[(size_t)(h * HD + d0 + ty + i) * S_ + s0 + tx] = t[tx][ty + i];
}

// ============ 256x128-tile GEMM, 3-slot ring, 2 blocks/CU (T1+T2+T4+T5) ============
// C[M][N] = A[M][K] * BT[N][K]^T + bias.  512 thr = 8 waves (4M x 2N), wave = 64x64.
// Slot = 24KB; ring-3 = 72KB -> 2 blocks/CU.  Stage tile t+2 while computing t.
// vmcnt LEDGER (correct-by-construction, R3-proven): 3 loads/tile/wave; at step t the
// wait vmcnt(3) retires all but the newest 3 (= stage(t+2)) -> stage(t+1) is resident
// before step t+1's ds_reads.  Tail: vmcnt(0) then no-wait.
template <bool STG, int VMC>
__device__ __forceinline__ void tile_step(
    const char* slot, int aoff, int boff,
    const bf16_t* gA, const bf16_t* gB, int kst, size_t skA,
    char* stg_dst, f32x4 (&acc)[4][4]) {
  bf16x8 a[4], b[4];
#pragma unroll
  for (int mi = 0; mi < 4; ++mi) a[mi] = *(const bf16x8*)(slot + aoff + mi * 1024);
#pragma unroll
  for (int ni = 0; ni < 4; ++ni) b[ni] = *(const bf16x8*)(slot + 16384 + boff + ni * 1024);
  if constexpr (STG) {
    __builtin_amdgcn_global_load_lds((const AS1 void*)(gA + kst), (AS3 void*)(stg_dst), 16, 0, 0);
    __builtin_amdgcn_global_load_lds((const AS1 void*)(gA + skA + kst), (AS3 void*)(stg_dst + 8192), 16, 0, 0);
    __builtin_amdgcn_global_load_lds((const AS1 void*)(gB + kst), (AS3 void*)(stg_dst + 16384), 16, 0, 0);
  }
  if constexpr (VMC == 3) asm volatile("s_waitcnt vmcnt(3)" ::: "memory");
  else if constexpr (VMC == 0) asm volatile("s_waitcnt vmcnt(0)" ::: "memory");
  __builtin_amdgcn_s_barrier();
  __builtin_amdgcn_s_setprio(1);
#pragma unroll
  for (int mi = 0; mi < 4; ++mi)
#pragma unroll
    for (int ni = 0; ni < 4; ++ni)
      acc[mi][ni] = __builtin_amdgcn_mfma_f32_16x16x32_bf16(a[mi], b[ni], acc[mi][ni], 0, 0, 0);
  __builtin_amdgcn_s_setprio(0);
  __builtin_amdgcn_s_barrier();
}

template <typename OutT>
__global__ __launch_bounds__(512, 4) void gemm_p(
    const bf16_t* __restrict__ A, const bf16_t* __restrict__ BT,
    const float* __restrict__ bias, OutT* __restrict__ C,
    int M, int N, int K) {
  extern __shared__ char smem[];
  const int tid = threadIdx.x;
  const int wv = tid >> 6, ln = tid & 63;
  const int lr = ln & 15, lg = ln >> 4;
  const int wm = wv >> 1, wn = wv & 1;

  const int nx = N >> 7;
  const int qx = gridDim.x >> 3;
  const int wg = (blockIdx.x & 7) * qx + (blockIdx.x >> 3);  // XCD-contiguous
  const int m0 = (wg / nx) * 256, n0 = (wg % nx) * 128;

  // staging: linear LDS dest; per-lane inverse-swizzled global source
  const int lrow = wv * 16 + (ln >> 2);
  const int lcol = ((ln & 3) << 3) ^ ((ln & 32) >> 1);
  const bf16_t* gA = A + (size_t)(m0 + lrow) * K + lcol;
  const bf16_t* gB = BT + (size_t)(n0 + lrow) * K + lcol;
  const size_t skA = (size_t)128 * K;

  // swizzled frag-read offsets: byte = row*64 + (lg*16 ^ (32 if row&8 (=lr&8)))
  const int sw = (lr & 8) << 2;
  const int aoff = (wm * 64 + lr) * 64 + ((lg * 16) ^ sw);
  const int boff = (wn * 64 + lr) * 64 + ((lg * 16) ^ sw);

  f32x4 acc[4][4] = {};

  // prologue: stage tiles 0,1 (6 loads/wave); vmcnt(3) retires t0, keeps t1 in flight
#pragma unroll
  for (int t = 0; t < 2; ++t) {
    char* d = smem + t * 24576 + wv * 1024;
    __builtin_amdgcn_global_load_lds((const AS1 void*)(gA + t * 32), (AS3 void*)(d), 16, 0, 0);
    __builtin_amdgcn_global_load_lds((const AS1 void*)(gA + skA + t * 32), (AS3 void*)(d + 8192), 16, 0, 0);
    __builtin_amdgcn_global_load_lds((const AS1 void*)(gB + t * 32), (AS3 void*)(d + 16384), 16, 0, 0);
  }
  asm volatile("s_waitcnt vmcnt(3)" ::: "memory");
  __builtin_amdgcn_s_barrier();

  const int NT = K >> 5;  // 128
  int slot = 0, nslot = 2;
  int t = 0;
  for (; t < NT - 2; ++t) {
    tile_step<true, 3>(smem + slot * 24576, aoff, boff, gA, gB, (t + 2) * 32,
                       skA, smem + nslot * 24576 + wv * 1024, acc);
    slot = (slot == 2) ? 0 : slot + 1;
    nslot = (nslot == 2) ? 0 : nslot + 1;
  }
  tile_step<false, 0>(smem + slot * 24576, aoff, boff, gA, gB, 0, skA, smem, acc);
  slot = (slot == 2) ? 0 : slot + 1;
  tile_step<false, -1>(smem + slot * 24576, aoff, boff, gA, gB, 0, skA, smem, acc);

#pragma unroll
  for (int mi = 0; mi < 4; ++mi)
#pragma unroll
    for (int ni = 0; ni < 4; ++ni) {
      const int col = n0 + wn * 64 + ni * 16 + lr;
      const float bv = bias[col];
#pragma unroll
      for (int i = 0; i < 4; ++i) {
        const int row = m0 + wm * 64 + mi * 16 + lg * 4 + i;
        C[(size_t)row * N + col] = (OutT)(acc[mi][ni][i] + bv);
      }
    }
}

// ---------------- flash attention: causal, 32 heads, d=128, QBLK=128 ----------------
// block = (q-tile of 128 rows, head); 4 waves x 32 rows (2 row-groups of 16); KV tile 64.
// K/V LDS fragments shared across row-groups -> bytes/MFMA halves vs QBLK=64.
// LDS: Ks 17408B (P overlaid: 4 waves x [32][68]) + Vts 18432B = 35840B; 2 blocks/CU.
__global__ __launch_bounds__(256, 2) void attn_fwd(
    const bf16_t* __restrict__ qkv, const bf16_t* __restrict__ vt,
    bf16_t* __restrict__ ctx) {
  __shared__ __align__(16) bf16_t Ks[64][136];    // K rows (kv), 272B stride
  __shared__ __align__(16) bf16_t Vts[128][72];   // V^T rows (d), 144B stride

  const int tid = threadIdx.x;
  const int wv = tid >> 6, ln = tid & 63;
  // P overlay on Ks: per-wave [32][68] bf16 = 4352B; 4 waves = 17408B = sizeof(Ks)
  bf16_t* Pl = &Ks[0][0] + wv * (32 * 68);

  // block decode: grid 512 = 8 xcd * (16 qt * 4 hsub). h = 4*xcd + hsub (L2 locality);
  // qt spread so co-resident blocks mix tile counts.
  const int bid = blockIdx.x;
  const int a = bid >> 3;
  const int hsub = a >> 4;
  const int h  = ((bid & 7) << 2) + hsub;
  const int qt = 15 - (((a & 15) + (hsub << 2)) & 15);
  const int q0 = qt * 128;
  const int lr = ln & 15, lg = ln >> 4;
  const int rbase = q0 + 32 * wv;   // wave's 32 rows: rbase + 16*rg + (lg*4+i)

  // Q fragments (scale folded), 2 row-groups
  bf16x8 qf[2][4];
#pragma unroll
  for (int rg = 0; rg < 2; ++rg)
#pragma unroll
    for (int kk = 0; kk < 4; ++kk) {
      bf16x8 r = *(const bf16x8*)(qkv + (size_t)(rbase + 16 * rg + lr) * N3 + h * HD + kk * 32 + lg * 8);
#pragma unroll
      for (int j = 0; j < 8; ++j) r[j] = (bf16_t)((float)r[j] * SCALE);
      qf[rg][kk] = r;
    }

  f32x4 oacc[2][8] = {};
  float mrow[2][4], psum[2][4];
#pragma unroll
  for (int rg = 0; rg < 2; ++rg)
#pragma unroll
    for (int i = 0; i < 4; ++i) { mrow[rg][i] = -INFINITY; psum[rg][i] = 0.f; }

  const int ntiles = 2 * qt + 2;
  for (int t = 0; t < ntiles; ++t) {
    const int kv0 = t * 64;
    __syncthreads();
#pragma unroll
    for (int it = 0; it < 4; ++it) {
      int c = tid + it * 256;
      {
        int row = c >> 4, col = (c & 15) * 8;
        *(bf16x8*)&Ks[row][col] =
            *(const bf16x8*)(qkv + (size_t)(kv0 + row) * N3 + HID + h * HD + col);
      }
      {
        int row = c >> 3, col = (c & 7) * 8;
        *(bf16x8*)&Vts[row][col] =
            *(const bf16x8*)(vt + (size_t)(h * HD + row) * S_ + kv0 + col);
      }
    }
    __syncthreads();

    // S = Q K^T  (K-fragments shared across both row-groups)
    f32x4 sacc[2][4] = {};
#pragma unroll
    for (int kk = 0; kk < 4; ++kk)
#pragma unroll
      for (int ni = 0; ni < 4; ++ni) {
        bf16x8 kf = *(const bf16x8*)&Ks[16 * ni + lr][kk * 32 + lg * 8];
        sacc[0][ni] = __builtin_amdgcn_mfma_f32_16x16x32_bf16(qf[0][kk], kf, sacc[0][ni], 0, 0, 0);
        sacc[1][ni] = __builtin_amdgcn_mfma_f32_16x16x32_bf16(qf[1][kk], kf, sacc[1][ni], 0, 0, 0);
      }

    // online softmax per row-group
    float p[2][4][4];
    float mx[2][4];
    bool grow = false;
#pragma unroll
    for (int rg = 0; rg < 2; ++rg) {
      const bool needmask = (kv0 + 63 > rbase + 16 * rg);
#pragma unroll
      for (int i = 0; i < 4; ++i) {
        const int row = rbase + 16 * rg + lg * 4 + i;
        float m_ = -INFINITY;
#pragma unroll
        for (int ni = 0; ni < 4; ++ni) {
          float s = sacc[rg][ni][i];
          if (needmask && (kv0 + 16 * ni + lr > row)) s = -INFINITY;
          p[rg][ni][i] = s;
          m_ = fmaxf(m_, s);
        }
        m_ = fmaxf(m_, __shfl_xor(m_, 1, 64));
        m_ = fmaxf(m_, __shfl_xor(m_, 2, 64));
        m_ = fmaxf(m_, __shfl_xor(m_, 4, 64));
        m_ = fmaxf(m_, __shfl_xor(m_, 8, 64));
        mx[rg][i] = m_;
        grow |= (m_ > mrow[rg][i]);
      }
    }
    if (__any(grow)) {
#pragma unroll
      for (int rg = 0; rg < 2; ++rg) {
        float alpha[4];
#pragma unroll
        for (int i = 0; i < 4; ++i) {
          const float mn = fmaxf(mrow[rg][i], mx[rg][i]);
          alpha[i] = __expf(mrow[rg][i] - mn);
          mrow[rg][i] = mn;
          psum[rg][i] *= alpha[i];
        }
#pragma unroll
        for (int nf = 0; nf < 8; ++nf)
#pragma unroll
          for (int i = 0; i < 4; ++i) oacc[rg][nf][i] *= alpha[i];
      }
    }
#pragma unroll
    for (int rg = 0; rg < 2; ++rg)
#pragma unroll
      for (int i = 0; i < 4; ++i) {
        float ps = 0.f;
#pragma unroll
        for (int ni = 0; ni < 4; ++ni) {
          float e = __expf(p[rg][ni][i] - mrow[rg][i]);
          p[rg][ni][i] = e;
          ps += e;
        }
        psum[rg][i] += ps;
      }

    __syncthreads();  // all waves done reading Ks -> safe to overwrite with P

    // P (C-layout) -> per-wave LDS slice [32][68] -> A-fragment layout
#pragma unroll
    for (int rg = 0; rg < 2; ++rg)
#pragma unroll
      for (int ni = 0; ni < 4; ++ni)
#pragma unroll
        for (int i = 0; i < 4; ++i)
          Pl[(16 * rg + lg * 4 + i) * 68 + 16 * ni + lr] = (bf16_t)p[rg][ni][i];

    // PV: V-fragments shared across row-groups
#pragma unroll
    for (int kk2 = 0; kk2 < 2; ++kk2) {
      bf16x8 pf0 = *(const bf16x8*)&Pl[lr * 68 + kk2 * 32 + lg * 8];
      bf16x8 pf1 = *(const bf16x8*)&Pl[(16 + lr) * 68 + kk2 * 32 + lg * 8];
#pragma unroll
      for (int nf = 0; nf < 8; ++nf) {
        bf16x8 vf = *(const bf16x8*)&Vts[16 * nf + lr][kk2 * 32 + lg * 8];
        oacc[0][nf] = __builtin_amdgcn_mfma_f32_16x16x32_bf16(pf0, vf, oacc[0][nf], 0, 0, 0);
        oacc[1][nf] = __builtin_amdgcn_mfma_f32_16x16x32_bf16(pf1, vf, oacc[1][nf], 0, 0, 0);
      }
    }
  }

  // epilogue
#pragma unroll
  for (int rg = 0; rg < 2; ++rg) {
#pragma unroll
    for (int i = 0; i < 4; ++i) {
      float s = psum[rg][i];
      s += __shfl_xor(s, 1, 64);
      s += __shfl_xor(s, 2, 64);
      s += __shfl_xor(s, 4, 64);
      s += __shfl_xor(s, 8, 64);
      psum[rg][i] = 1.f / s;
    }
#pragma unroll
    for (int nf = 0; nf < 8; ++nf)
#pragma unroll
      for (int i = 0; i < 4; ++i) {
        int row = rbase + 16 * rg + lg * 4 + i;
        int col = h * HD + 16 * nf + lr;
        ctx[(size_t)row * HID + col] = (bf16_t)(oacc[rg][nf][i] * psum[rg][i]);
      }
  }
}

// ---------------- launcher ----------------
extern "C" void kernel_launch(void* const* d_in, const int* in_sizes, int n_in,
                              void* d_out, int out_size, void* d_ws, size_t ws_size,
                              hipStream_t stream) {
  const float* x    = (const float*)d_in[0];
  const float* wqkv = (const float*)d_in[1];
  const float* bqkv = (const float*)d_in[2];
  const float* ow   = (const float*)d_in[3];
  const float* ob   = (const float*)d_in[4];
  float* out = (float*)d_out;

  char* w = (char*)d_ws;
  bf16_t* xb    = (bf16_t*)(w);                          // S*HID       bf16 (16 MB)
  bf16_t* wqkvT = (bf16_t*)(w + (size_t)16777216);       // N3*HID      bf16 (100.7 MB)
  bf16_t* qkv   = (bf16_t*)(w + (size_t)117440512);      // S*N3        bf16 (50.3 MB)
  bf16_t* vt    = (bf16_t*)(w + (size_t)167772160);      // NH*HD*S     bf16 (16 MB)
  bf16_t* ctx   = (bf16_t*)(w + (size_t)184549376);      // S*HID       bf16 (16 MB)
  bf16_t* owT   = (bf16_t*)(w + (size_t)201326592);      // HID*HID     bf16 (33.6 MB)

  (void)in_sizes; (void)n_in; (void)out_size; (void)ws_size;

  cvt_f32_bf16<<<(S_ * HID / 4 + 255) / 256, 256, 0, stream>>>(x, xb, S_ * HID / 4);
  transcvt64<<<dim3(N3 / 64, HID / 64), 256, 0, stream>>>(wqkv, wqkvT, HID, N3);
  transcvt64<<<dim3(HID / 64, HID / 64), 256, 0, stream>>>(ow, owT, HID, HID);
  // QKV projection: grid 8*96=768 (3 exact rounds at 2 blocks/CU), 72KB dynamic LDS
  gemm_p<bf16_t><<<(S_ / 256) * (N3 / 128), 512, 73728, stream>>>(xb, wqkvT, bqkv, qkv, S_, N3, HID);
  vtrans<<<dim3(S_ / 32, HD / 32, NH), dim3(32, 8), 0, stream>>>(qkv, vt);
  // attention: QBLK=128, grid 16*32=512 (%8==0), 2 blocks/CU
  attn_fwd<<<(S_ / 128) * NH, 256, 0, stream>>>(qkv, vt, ctx);
  // out projection: 256x128 tile, grid 8*32=256 (1 exact round at 2/CU)
  gemm_p<float><<<(S_ / 256) * (HID / 128), 512, 73728, stream>>>(ctx, owT, ob, out, S_, HID, HID);
}

// Round 7
// 510.349 us; speedup vs baseline: 1.5235x; 1.0196x over previous
//
#include <hip/hip_runtime.h>
#include <hip/hip_bf16.h>
#include <math.h>

typedef __bf16 bf16_t;
typedef __bf16 bf16x8 __attribute__((ext_vector_type(8)));
typedef float f32x4 __attribute__((ext_vector_type(4)));

#define AS1 __attribute__((address_space(1)))
#define AS3 __attribute__((address_space(3)))

static constexpr int S_  = 2048;
static constexpr int HID = 4096;
static constexpr int NH  = 32;
static constexpr int HD  = 128;
static constexpr int N3  = 3 * HID;           // 12288
static constexpr float SCALE = 0.08838834764831845f;  // 1/sqrt(128)

// ---------------- fp32 -> bf16 convert (vectorized) ----------------
__global__ void cvt_f32_bf16(const float* __restrict__ in, bf16_t* __restrict__ out, int n4) {
  int i = blockIdx.x * blockDim.x + threadIdx.x;
  if (i >= n4) return;
  float4 v = ((const float4*)in)[i];
  union { bf16_t h[4]; short4 s4; } u;
  u.h[0] = (bf16_t)v.x; u.h[1] = (bf16_t)v.y; u.h[2] = (bf16_t)v.z; u.h[3] = (bf16_t)v.w;
  ((short4*)out)[i] = u.s4;
}

// ------- transpose + convert: in[R][C] f32 -> out[C][R] bf16, 64x64 tile -------
__global__ __launch_bounds__(256) void transcvt64(
    const float* __restrict__ in, bf16_t* __restrict__ out, int R, int C) {
  __shared__ float t[64][65];
  const int r0 = blockIdx.y * 64, c0 = blockIdx.x * 64;
  const int tid = threadIdx.x;
  const int rr = tid >> 4, c4 = (tid & 15) * 4;   // 16 rows/iter x 16 float4
#pragma unroll
  for (int it = 0; it < 4; ++it) {
    float4 v = *(const float4*)&in[(size_t)(r0 + rr + it * 16) * C + c0 + c4];
    t[rr + it * 16][c4 + 0] = v.x;
    t[rr + it * 16][c4 + 1] = v.y;
    t[rr + it * 16][c4 + 2] = v.z;
    t[rr + it * 16][c4 + 3] = v.w;
  }
  __syncthreads();
  const int cc = tid >> 3, r8 = (tid & 7) * 8;    // 32 out-rows/iter x 8 chunks
#pragma unroll
  for (int it = 0; it < 2; ++it) {
    const int c = cc + it * 32;
    bf16x8 w;
#pragma unroll
    for (int j = 0; j < 8; ++j) w[j] = (bf16_t)t[r8 + j][c];
    *(bf16x8*)&out[(size_t)(c0 + c) * R + r0 + r8] = w;
  }
}

// ------- per-head V transpose: qkv[s][2*HID + h*HD + d] -> vt[(h*HD+d)*S + s] -------
__global__ void vtrans(const bf16_t* __restrict__ qkv, bf16_t* __restrict__ vt) {
  __shared__ bf16_t t[32][33];
  int h = blockIdx.z;
  int s0 = blockIdx.x * 32, d0 = blockIdx.y * 32;
  int tx = threadIdx.x, ty = threadIdx.y;  // 32 x 8
#pragma unroll
  for (int i = 0; i < 32; i += 8)
    t[ty + i][tx] = qkv[(size_t)(s0 + ty + i) * N3 + 2 * HID + h * HD + d0 + tx];
  __syncthreads();
#pragma unroll
  for (int i = 0; i < 32; i += 8)
    vt[(size_t)(h * HD + d0 + ty + i) * S_ + s0 + tx] = t[tx][ty + i];
}

// ====== 256x128-tile GEMM, ring-3, PERSISTENT grid-stride tile loop ======
// 512 thr = 8 waves (4M x 2N), wave = 64x64.  Slot = 24KB; ring-3 = 72KB -> 2 blk/CU.
// Persistent: grid = min(2*#CU, ntiles); block b handles tiles b, b+gridDim, ...
// (dispatch fills slot-1 across CUs then slot-2 -> CU c hosts blocks {c, c+256};
//  for gemm1 each CU gets exactly 3 tiles -> no ragged half-round).
// vmcnt ledger (proven R3/R6): 3 loads/tile/wave; steady vmcnt(3) retires stage(t),
// keeps stage(t+1) in flight; tail vmcnt(0) then none; all retired before next
// tile's prologue, whose vmcnt(3) therefore counts only its own 6 loads.
template <bool STG, int VMC>
__device__ __forceinline__ void tile_step(
    const char* slot, int aoff, int boff,
    const bf16_t* gA, const bf16_t* gB, int kst, size_t skA,
    char* stg_dst, f32x4 (&acc)[4][4]) {
  bf16x8 a[4], b[4];
#pragma unroll
  for (int mi = 0; mi < 4; ++mi) a[mi] = *(const bf16x8*)(slot + aoff + mi * 1024);
#pragma unroll
  for (int ni = 0; ni < 4; ++ni) b[ni] = *(const bf16x8*)(slot + 16384 + boff + ni * 1024);
  if constexpr (STG) {
    __builtin_amdgcn_global_load_lds((const AS1 void*)(gA + kst), (AS3 void*)(stg_dst), 16, 0, 0);
    __builtin_amdgcn_global_load_lds((const AS1 void*)(gA + skA + kst), (AS3 void*)(stg_dst + 8192), 16, 0, 0);
    __builtin_amdgcn_global_load_lds((const AS1 void*)(gB + kst), (AS3 void*)(stg_dst + 16384), 16, 0, 0);
  }
  if constexpr (VMC == 3) asm volatile("s_waitcnt vmcnt(3)" ::: "memory");
  else if constexpr (VMC == 0) asm volatile("s_waitcnt vmcnt(0)" ::: "memory");
  __builtin_amdgcn_s_barrier();
  __builtin_amdgcn_s_setprio(1);
#pragma unroll
  for (int mi = 0; mi < 4; ++mi)
#pragma unroll
    for (int ni = 0; ni < 4; ++ni)
      acc[mi][ni] = __builtin_amdgcn_mfma_f32_16x16x32_bf16(a[mi], b[ni], acc[mi][ni], 0, 0, 0);
  __builtin_amdgcn_s_setprio(0);
  __builtin_amdgcn_s_barrier();
}

template <typename OutT>
__global__ __launch_bounds__(512, 4) void gemm_p(
    const bf16_t* __restrict__ A, const bf16_t* __restrict__ BT,
    const float* __restrict__ bias, OutT* __restrict__ C,
    int M, int N, int K, int ntiles) {
  extern __shared__ char smem[];
  const int tid = threadIdx.x;
  const int wv = tid >> 6, ln = tid & 63;
  const int lr = ln & 15, lg = ln >> 4;
  const int wm = wv >> 1, wn = wv & 1;

  const int nx = N >> 7;
  const int chunk = ntiles >> 3;  // tiles per XCD (ntiles % 8 == 0)

  // staging lane geometry (tile-independent)
  const int lrow = wv * 16 + (ln >> 2);
  const int lcol = ((ln & 3) << 3) ^ ((ln & 32) >> 1);
  const size_t skA = (size_t)128 * K;
  // swizzled frag-read offsets
  const int sw = (lr & 8) << 2;
  const int aoff = (wm * 64 + lr) * 64 + ((lg * 16) ^ sw);
  const int boff = (wn * 64 + lr) * 64 + ((lg * 16) ^ sw);
  const int NT = K >> 5;

  for (int tt = blockIdx.x; tt < ntiles; tt += gridDim.x) {
    // XCD swizzle on tile id: chunk per XCD is contiguous (= one M-row when
    // chunk == nx, giving A-panel L2 reuse across a block's tiles)
    const int wg = (tt & 7) * chunk + (tt >> 3);
    const int m0 = (wg / nx) * 256, n0 = (wg % nx) * 128;

    const bf16_t* gA = A + (size_t)(m0 + lrow) * K + lcol;
    const bf16_t* gB = BT + (size_t)(n0 + lrow) * K + lcol;

    f32x4 acc[4][4] = {};

    // prologue: stage tiles 0,1; vmcnt(3) retires t0, keeps t1 in flight
#pragma unroll
    for (int t = 0; t < 2; ++t) {
      char* d = smem + t * 24576 + wv * 1024;
      __builtin_amdgcn_global_load_lds((const AS1 void*)(gA + t * 32), (AS3 void*)(d), 16, 0, 0);
      __builtin_amdgcn_global_load_lds((const AS1 void*)(gA + skA + t * 32), (AS3 void*)(d + 8192), 16, 0, 0);
      __builtin_amdgcn_global_load_lds((const AS1 void*)(gB + t * 32), (AS3 void*)(d + 16384), 16, 0, 0);
    }
    asm volatile("s_waitcnt vmcnt(3)" ::: "memory");
    __builtin_amdgcn_s_barrier();

    int slot = 0, nslot = 2;
    int t = 0;
    for (; t < NT - 2; ++t) {
      tile_step<true, 3>(smem + slot * 24576, aoff, boff, gA, gB, (t + 2) * 32,
                         skA, smem + nslot * 24576 + wv * 1024, acc);
      slot = (slot == 2) ? 0 : slot + 1;
      nslot = (nslot == 2) ? 0 : nslot + 1;
    }
    tile_step<false, 0>(smem + slot * 24576, aoff, boff, gA, gB, 0, skA, smem, acc);
    slot = (slot == 2) ? 0 : slot + 1;
    tile_step<false, -1>(smem + slot * 24576, aoff, boff, gA, gB, 0, skA, smem, acc);

    // epilogue
#pragma unroll
    for (int mi = 0; mi < 4; ++mi)
#pragma unroll
      for (int ni = 0; ni < 4; ++ni) {
        const int col = n0 + wn * 64 + ni * 16 + lr;
        const float bv = bias[col];
#pragma unroll
        for (int i = 0; i < 4; ++i) {
          const int row = m0 + wm * 64 + mi * 16 + lg * 4 + i;
          C[(size_t)row * N + col] = (OutT)(acc[mi][ni][i] + bv);
        }
      }
  }
}

// ---------------- flash attention: causal, 32 heads, d=128, QBLK=128 ----------------
// block = (q-tile of 128 rows, head); 4 waves x 32 rows (2 row-groups of 16); KV tile 64.
// LDS: Ks 17408B (P overlaid: 4 waves x [32][68]) + Vts 18432B = 35840B; 2 blocks/CU.
__global__ __launch_bounds__(256, 2) void attn_fwd(
    const bf16_t* __restrict__ qkv, const bf16_t* __restrict__ vt,
    bf16_t* __restrict__ ctx) {
  __shared__ __align__(16) bf16_t Ks[64][136];    // K rows (kv), 272B stride
  __shared__ __align__(16) bf16_t Vts[128][72];   // V^T rows (d), 144B stride

  const int tid = threadIdx.x;
  const int wv = tid >> 6, ln = tid & 63;
  bf16_t* Pl = &Ks[0][0] + wv * (32 * 68);

  const int bid = blockIdx.x;
  const int a = bid >> 3;
  const int hsub = a >> 4;
  const int h  = ((bid & 7) << 2) + hsub;
  const int qt = 15 - (((a & 15) + (hsub << 2)) & 15);
  const int q0 = qt * 128;
  const int lr = ln & 15, lg = ln >> 4;
  const int rbase = q0 + 32 * wv;

  bf16x8 qf[2][4];
#pragma unroll
  for (int rg = 0; rg < 2; ++rg)
#pragma unroll
    for (int kk = 0; kk < 4; ++kk) {
      bf16x8 r = *(const bf16x8*)(qkv + (size_t)(rbase + 16 * rg + lr) * N3 + h * HD + kk * 32 + lg * 8);
#pragma unroll
      for (int j = 0; j < 8; ++j) r[j] = (bf16_t)((float)r[j] * SCALE);
      qf[rg][kk] = r;
    }

  f32x4 oacc[2][8] = {};
  float mrow[2][4], psum[2][4];
#pragma unroll
  for (int rg = 0; rg < 2; ++rg)
#pragma unroll
    for (int i = 0; i < 4; ++i) { mrow[rg][i] = -INFINITY; psum[rg][i] = 0.f; }

  const int ntiles = 2 * qt + 2;
  for (int t = 0; t < ntiles; ++t) {
    const int kv0 = t * 64;
    __syncthreads();
#pragma unroll
    for (int it = 0; it < 4; ++it) {
      int c = tid + it * 256;
      {
        int row = c >> 4, col = (c & 15) * 8;
        *(bf16x8*)&Ks[row][col] =
            *(const bf16x8*)(qkv + (size_t)(kv0 + row) * N3 + HID + h * HD + col);
      }
      {
        int row = c >> 3, col = (c & 7) * 8;
        *(bf16x8*)&Vts[row][col] =
            *(const bf16x8*)(vt + (size_t)(h * HD + row) * S_ + kv0 + col);
      }
    }
    __syncthreads();

    f32x4 sacc[2][4] = {};
#pragma unroll
    for (int kk = 0; kk < 4; ++kk)
#pragma unroll
      for (int ni = 0; ni < 4; ++ni) {
        bf16x8 kf = *(const bf16x8*)&Ks[16 * ni + lr][kk * 32 + lg * 8];
        sacc[0][ni] = __builtin_amdgcn_mfma_f32_16x16x32_bf16(qf[0][kk], kf, sacc[0][ni], 0, 0, 0);
        sacc[1][ni] = __builtin_amdgcn_mfma_f32_16x16x32_bf16(qf[1][kk], kf, sacc[1][ni], 0, 0, 0);
      }

    float p[2][4][4];
    float mx[2][4];
    bool grow = false;
#pragma unroll
    for (int rg = 0; rg < 2; ++rg) {
      const bool needmask = (kv0 + 63 > rbase + 16 * rg);
#pragma unroll
      for (int i = 0; i < 4; ++i) {
        const int row = rbase + 16 * rg + lg * 4 + i;
        float m_ = -INFINITY;
#pragma unroll
        for (int ni = 0; ni < 4; ++ni) {
          float s = sacc[rg][ni][i];
          if (needmask && (kv0 + 16 * ni + lr > row)) s = -INFINITY;
          p[rg][ni][i] = s;
          m_ = fmaxf(m_, s);
        }
        m_ = fmaxf(m_, __shfl_xor(m_, 1, 64));
        m_ = fmaxf(m_, __shfl_xor(m_, 2, 64));
        m_ = fmaxf(m_, __shfl_xor(m_, 4, 64));
        m_ = fmaxf(m_, __shfl_xor(m_, 8, 64));
        mx[rg][i] = m_;
        grow |= (m_ > mrow[rg][i]);
      }
    }
    if (__any(grow)) {
#pragma unroll
      for (int rg = 0; rg < 2; ++rg) {
        float alpha[4];
#pragma unroll
        for (int i = 0; i < 4; ++i) {
          const float mn = fmaxf(mrow[rg][i], mx[rg][i]);
          alpha[i] = __expf(mrow[rg][i] - mn);
          mrow[rg][i] = mn;
          psum[rg][i] *= alpha[i];
        }
#pragma unroll
        for (int nf = 0; nf < 8; ++nf)
#pragma unroll
          for (int i = 0; i < 4; ++i) oacc[rg][nf][i] *= alpha[i];
      }
    }
#pragma unroll
    for (int rg = 0; rg < 2; ++rg)
#pragma unroll
      for (int i = 0; i < 4; ++i) {
        float ps = 0.f;
#pragma unroll
        for (int ni = 0; ni < 4; ++ni) {
          float e = __expf(p[rg][ni][i] - mrow[rg][i]);
          p[rg][ni][i] = e;
          ps += e;
        }
        psum[rg][i] += ps;
      }

    __syncthreads();

#pragma unroll
    for (int rg = 0; rg < 2; ++rg)
#pragma unroll
      for (int ni = 0; ni < 4; ++ni)
#pragma unroll
        for (int i = 0; i < 4; ++i)
          Pl[(16 * rg + lg * 4 + i) * 68 + 16 * ni + lr] = (bf16_t)p[rg][ni][i];

#pragma unroll
    for (int kk2 = 0; kk2 < 2; ++kk2) {
      bf16x8 pf0 = *(const bf16x8*)&Pl[lr * 68 + kk2 * 32 + lg * 8];
      bf16x8 pf1 = *(const bf16x8*)&Pl[(16 + lr) * 68 + kk2 * 32 + lg * 8];
#pragma unroll
      for (int nf = 0; nf < 8; ++nf) {
        bf16x8 vf = *(const bf16x8*)&Vts[16 * nf + lr][kk2 * 32 + lg * 8];
        oacc[0][nf] = __builtin_amdgcn_mfma_f32_16x16x32_bf16(pf0, vf, oacc[0][nf], 0, 0, 0);
        oacc[1][nf] = __builtin_amdgcn_mfma_f32_16x16x32_bf16(pf1, vf, oacc[1][nf], 0, 0, 0);
      }
    }
  }

#pragma unroll
  for (int rg = 0; rg < 2; ++rg) {
#pragma unroll
    for (int i = 0; i < 4; ++i) {
      float s = psum[rg][i];
      s += __shfl_xor(s, 1, 64);
      s += __shfl_xor(s, 2, 64);
      s += __shfl_xor(s, 4, 64);
      s += __shfl_xor(s, 8, 64);
      psum[rg][i] = 1.f / s;
    }
#pragma unroll
    for (int nf = 0; nf < 8; ++nf)
#pragma unroll
      for (int i = 0; i < 4; ++i) {
        int row = rbase + 16 * rg + lg * 4 + i;
        int col = h * HD + 16 * nf + lr;
        ctx[(size_t)row * HID + col] = (bf16_t)(oacc[rg][nf][i] * psum[rg][i]);
      }
  }
}

// ---------------- launcher ----------------
extern "C" void kernel_launch(void* const* d_in, const int* in_sizes, int n_in,
                              void* d_out, int out_size, void* d_ws, size_t ws_size,
                              hipStream_t stream) {
  const float* x    = (const float*)d_in[0];
  const float* wqkv = (const float*)d_in[1];
  const float* bqkv = (const float*)d_in[2];
  const float* ow   = (const float*)d_in[3];
  const float* ob   = (const float*)d_in[4];
  float* out = (float*)d_out;

  char* w = (char*)d_ws;
  bf16_t* xb    = (bf16_t*)(w);                          // S*HID       bf16 (16 MB)
  bf16_t* wqkvT = (bf16_t*)(w + (size_t)16777216);       // N3*HID      bf16 (100.7 MB)
  bf16_t* qkv   = (bf16_t*)(w + (size_t)117440512);      // S*N3        bf16 (50.3 MB)
  bf16_t* vt    = (bf16_t*)(w + (size_t)167772160);      // NH*HD*S     bf16 (16 MB)
  bf16_t* ctx   = (bf16_t*)(w + (size_t)184549376);      // S*HID       bf16 (16 MB)
  bf16_t* owT   = (bf16_t*)(w + (size_t)201326592);      // HID*HID     bf16 (33.6 MB)

  (void)in_sizes; (void)n_in; (void)out_size; (void)ws_size;

  cvt_f32_bf16<<<(S_ * HID / 4 + 255) / 256, 256, 0, stream>>>(x, xb, S_ * HID / 4);
  transcvt64<<<dim3(N3 / 64, HID / 64), 256, 0, stream>>>(wqkv, wqkvT, HID, N3);
  transcvt64<<<dim3(HID / 64, HID / 64), 256, 0, stream>>>(ow, owT, HID, HID);
  // QKV projection: 768 tiles, persistent 512 blocks (2/CU, 3 tiles per CU exact)
  gemm_p<bf16_t><<<512, 512, 73728, stream>>>(xb, wqkvT, bqkv, qkv, S_, N3, HID,
                                              (S_ / 256) * (N3 / 128));
  vtrans<<<dim3(S_ / 32, HD / 32, NH), dim3(32, 8), 0, stream>>>(qkv, vt);
  // attention: QBLK=128, grid 16*32=512 (%8==0), 2 blocks/CU
  attn_fwd<<<(S_ / 128) * NH, 256, 0, stream>>>(qkv, vt, ctx);
  // out projection: 256 tiles, 256 blocks (1/CU, 1 tile each)
  gemm_p<float><<<256, 512, 73728, stream>>>(ctx, owT, ob, out, S_, HID, HID,
                                             (S_ / 256) * (HID / 128));
}

// Round 8
// 508.175 us; speedup vs baseline: 1.5300x; 1.0043x over previous
//
#include <hip/hip_runtime.h>
#include <hip/hip_bf16.h>
#include <math.h>

typedef __bf16 bf16_t;
typedef __bf16 bf16x8 __attribute__((ext_vector_type(8)));
typedef float f32x4 __attribute__((ext_vector_type(4)));

#define AS1 __attribute__((address_space(1)))
#define AS3 __attribute__((address_space(3)))

static constexpr int S_  = 2048;
static constexpr int HID = 4096;
static constexpr int NH  = 32;
static constexpr int HD  = 128;
static constexpr int N3  = 3 * HID;           // 12288
static constexpr float SCALE = 0.08838834764831845f;  // 1/sqrt(128)

// ---------------- fp32 -> bf16 convert (vectorized) ----------------
__global__ void cvt_f32_bf16(const float* __restrict__ in, bf16_t* __restrict__ out, int n4) {
  int i = blockIdx.x * blockDim.x + threadIdx.x;
  if (i >= n4) return;
  float4 v = ((const float4*)in)[i];
  union { bf16_t h[4]; short4 s4; } u;
  u.h[0] = (bf16_t)v.x; u.h[1] = (bf16_t)v.y; u.h[2] = (bf16_t)v.z; u.h[3] = (bf16_t)v.w;
  ((short4*)out)[i] = u.s4;
}

// ------- transpose + convert: in[R][C] f32 -> out[C][R] bf16, 64x64 tile -------
__global__ __launch_bounds__(256) void transcvt64(
    const float* __restrict__ in, bf16_t* __restrict__ out, int R, int C) {
  __shared__ float t[64][65];
  const int r0 = blockIdx.y * 64, c0 = blockIdx.x * 64;
  const int tid = threadIdx.x;
  const int rr = tid >> 4, c4 = (tid & 15) * 4;   // 16 rows/iter x 16 float4
#pragma unroll
  for (int it = 0; it < 4; ++it) {
    float4 v = *(const float4*)&in[(size_t)(r0 + rr + it * 16) * C + c0 + c4];
    t[rr + it * 16][c4 + 0] = v.x;
    t[rr + it * 16][c4 + 1] = v.y;
    t[rr + it * 16][c4 + 2] = v.z;
    t[rr + it * 16][c4 + 3] = v.w;
  }
  __syncthreads();
  const int cc = tid >> 3, r8 = (tid & 7) * 8;    // 32 out-rows/iter x 8 chunks
#pragma unroll
  for (int it = 0; it < 2; ++it) {
    const int c = cc + it * 32;
    bf16x8 w;
#pragma unroll
    for (int j = 0; j < 8; ++j) w[j] = (bf16_t)t[r8 + j][c];
    *(bf16x8*)&out[(size_t)(c0 + c) * R + r0 + r8] = w;
  }
}

// ------- per-head V transpose: qkv[s][2*HID + h*HD + d] -> vt[(h*HD+d)*S + s] -------
__global__ void vtrans(const bf16_t* __restrict__ qkv, bf16_t* __restrict__ vt) {
  __shared__ bf16_t t[32][33];
  int h = blockIdx.z;
  int s0 = blockIdx.x * 32, d0 = blockIdx.y * 32;
  int tx = threadIdx.x, ty = threadIdx.y;  // 32 x 8
#pragma unroll
  for (int i = 0; i < 32; i += 8)
    t[ty + i][tx] = qkv[(size_t)(s0 + ty + i) * N3 + 2 * HID + h * HD + d0 + tx];
  __syncthreads();
#pragma unroll
  for (int i = 0; i < 32; i += 8)
    vt[(size_t)(h * HD + d0 + ty + i) * S_ + s0 + tx] = t[tx][ty + i];
}

// ====== gemm_w: 256x128 tile, 4 waves (2Mx2N) of 128x64, ring-3, persistent ======
// 256 thr.  Wave economy: (128+64)/(128*64) -> 24 B/kFLOP (vs 32 for 64x64 waves):
// per CU-K32step reads 96 b128 (~1150cy) vs MFMA 1024cy -> MFMA-bound-ish.
// Slot = 24KB (A 256x32: 16KB | B 128x32: 8KB); ring-3 = 72KB -> 2 blocks/CU.
// vmcnt ledger: 6 loads/tile/wave, 2-ahead; steady vmcnt(6) retires stage(t+1),
// keeps stage(t+2) in flight; tail vmcnt(0) then none.
template <bool STG, int VMC>
__device__ __forceinline__ void wstep(
    const char* slot, int aoff, int boff,
    const bf16_t* gA, const bf16_t* gB, int kst, size_t row64,
    char* stgA, char* stgB, f32x4 (&acc)[8][4]) {
  bf16x8 a[8], b[4];
#pragma unroll
  for (int mi = 0; mi < 8; ++mi) a[mi] = *(const bf16x8*)(slot + aoff + mi * 1024);
#pragma unroll
  for (int ni = 0; ni < 4; ++ni) b[ni] = *(const bf16x8*)(slot + 16384 + boff + ni * 1024);
  if constexpr (STG) {
#pragma unroll
    for (int i = 0; i < 4; ++i)
      __builtin_amdgcn_global_load_lds((const AS1 void*)(gA + i * row64 + kst),
                                       (AS3 void*)(stgA + i * 4096), 16, 0, 0);
#pragma unroll
    for (int j = 0; j < 2; ++j)
      __builtin_amdgcn_global_load_lds((const AS1 void*)(gB + j * row64 + kst),
                                       (AS3 void*)(stgB + j * 4096), 16, 0, 0);
  }
  if constexpr (VMC == 6) asm volatile("s_waitcnt vmcnt(6)" ::: "memory");
  else if constexpr (VMC == 0) asm volatile("s_waitcnt vmcnt(0)" ::: "memory");
  __builtin_amdgcn_s_barrier();
  __builtin_amdgcn_s_setprio(1);
#pragma unroll
  for (int mi = 0; mi < 8; ++mi)
#pragma unroll
    for (int ni = 0; ni < 4; ++ni)
      acc[mi][ni] = __builtin_amdgcn_mfma_f32_16x16x32_bf16(a[mi], b[ni], acc[mi][ni], 0, 0, 0);
  __builtin_amdgcn_s_setprio(0);
  __builtin_amdgcn_s_barrier();
}

__global__ __launch_bounds__(256, 2) void gemm_w(
    const bf16_t* __restrict__ A, const bf16_t* __restrict__ BT,
    const float* __restrict__ bias, bf16_t* __restrict__ C,
    int M, int N, int K, int ntiles) {
  extern __shared__ char smem[];
  const int tid = threadIdx.x;
  const int wv = tid >> 6, ln = tid & 63;
  const int lr = ln & 15, lg = ln >> 4;
  const int wm = wv >> 1, wn = wv & 1;

  const int nx = N >> 7;
  const int chunk = ntiles >> 3;  // ntiles % 8 == 0

  // staging lane geometry: dest byte (region) = wv*1024 + i*4096 + ln*16
  //   -> row = wv*16 + i*64 + (ln>>2); row-bit3 = ln&32 -> same inverse swizzle
  const int lrow = wv * 16 + (ln >> 2);
  const int lcol = ((ln & 3) << 3) ^ ((ln & 32) >> 1);
  const size_t row64 = (size_t)64 * K;
  // swizzled frag-read offsets: byte = row*64 + (lg*16 ^ (32 if row&8 (=lr&8)))
  const int sw = (lr & 8) << 2;
  const int aoff = (wm * 128 + lr) * 64 + ((lg * 16) ^ sw);
  const int boff = (wn * 64 + lr) * 64 + ((lg * 16) ^ sw);
  const int NT = K >> 5;

  for (int tt = blockIdx.x; tt < ntiles; tt += gridDim.x) {
    const int wg = (tt & 7) * chunk + (tt >> 3);  // XCD-contiguous chunks
    const int m0 = (wg / nx) * 256, n0 = (wg % nx) * 128;

    const bf16_t* gA = A + (size_t)(m0 + lrow) * K + lcol;
    const bf16_t* gB = BT + (size_t)(n0 + lrow) * K + lcol;

    f32x4 acc[8][4] = {};

    // prologue: stage tiles 0,1 (12 loads/wave); vmcnt(6) retires t0, keeps t1
#pragma unroll
    for (int t = 0; t < 2; ++t) {
      char* dA = smem + t * 24576 + wv * 1024;
      char* dB = dA + 16384;
#pragma unroll
      for (int i = 0; i < 4; ++i)
        __builtin_amdgcn_global_load_lds((const AS1 void*)(gA + i * row64 + t * 32),
                                         (AS3 void*)(dA + i * 4096), 16, 0, 0);
#pragma unroll
      for (int j = 0; j < 2; ++j)
        __builtin_amdgcn_global_load_lds((const AS1 void*)(gB + j * row64 + t * 32),
                                         (AS3 void*)(dB + j * 4096), 16, 0, 0);
    }
    asm volatile("s_waitcnt vmcnt(6)" ::: "memory");
    __builtin_amdgcn_s_barrier();

    int slot = 0, nslot = 2;
    int t = 0;
    for (; t < NT - 2; ++t) {
      char* sb = smem + nslot * 24576 + wv * 1024;
      wstep<true, 6>(smem + slot * 24576, aoff, boff, gA, gB, (t + 2) * 32,
                     row64, sb, sb + 16384, acc);
      slot = (slot == 2) ? 0 : slot + 1;
      nslot = (nslot == 2) ? 0 : nslot + 1;
    }
    wstep<false, 0>(smem + slot * 24576, aoff, boff, gA, gB, 0, row64, smem, smem, acc);
    slot = (slot == 2) ? 0 : slot + 1;
    wstep<false, -1>(smem + slot * 24576, aoff, boff, gA, gB, 0, row64, smem, smem, acc);

    // epilogue
#pragma unroll
    for (int mi = 0; mi < 8; ++mi)
#pragma unroll
      for (int ni = 0; ni < 4; ++ni) {
        const int col = n0 + wn * 64 + ni * 16 + lr;
        const float bv = bias[col];
#pragma unroll
        for (int i = 0; i < 4; ++i) {
          const int row = m0 + wm * 128 + mi * 16 + lg * 4 + i;
          C[(size_t)row * N + col] = (bf16_t)(acc[mi][ni][i] + bv);
        }
      }
  }
}

// ====== 256x128-tile GEMM, 8 waves of 64x64, ring-3, persistent (out-proj) ======
template <bool STG, int VMC>
__device__ __forceinline__ void tile_step(
    const char* slot, int aoff, int boff,
    const bf16_t* gA, const bf16_t* gB, int kst, size_t skA,
    char* stg_dst, f32x4 (&acc)[4][4]) {
  bf16x8 a[4], b[4];
#pragma unroll
  for (int mi = 0; mi < 4; ++mi) a[mi] = *(const bf16x8*)(slot + aoff + mi * 1024);
#pragma unroll
  for (int ni = 0; ni < 4; ++ni) b[ni] = *(const bf16x8*)(slot + 16384 + boff + ni * 1024);
  if constexpr (STG) {
    __builtin_amdgcn_global_load_lds((const AS1 void*)(gA + kst), (AS3 void*)(stg_dst), 16, 0, 0);
    __builtin_amdgcn_global_load_lds((const AS1 void*)(gA + skA + kst), (AS3 void*)(stg_dst + 8192), 16, 0, 0);
    __builtin_amdgcn_global_load_lds((const AS1 void*)(gB + kst), (AS3 void*)(stg_dst + 16384), 16, 0, 0);
  }
  if constexpr (VMC == 3) asm volatile("s_waitcnt vmcnt(3)" ::: "memory");
  else if constexpr (VMC == 0) asm volatile("s_waitcnt vmcnt(0)" ::: "memory");
  __builtin_amdgcn_s_barrier();
  __builtin_amdgcn_s_setprio(1);
#pragma unroll
  for (int mi = 0; mi < 4; ++mi)
#pragma unroll
    for (int ni = 0; ni < 4; ++ni)
      acc[mi][ni] = __builtin_amdgcn_mfma_f32_16x16x32_bf16(a[mi], b[ni], acc[mi][ni], 0, 0, 0);
  __builtin_amdgcn_s_setprio(0);
  __builtin_amdgcn_s_barrier();
}

template <typename OutT>
__global__ __launch_bounds__(512, 4) void gemm_p(
    const bf16_t* __restrict__ A, const bf16_t* __restrict__ BT,
    const float* __restrict__ bias, OutT* __restrict__ C,
    int M, int N, int K, int ntiles) {
  extern __shared__ char smem[];
  const int tid = threadIdx.x;
  const int wv = tid >> 6, ln = tid & 63;
  const int lr = ln & 15, lg = ln >> 4;
  const int wm = wv >> 1, wn = wv & 1;

  const int nx = N >> 7;
  const int chunk = ntiles >> 3;

  const int lrow = wv * 16 + (ln >> 2);
  const int lcol = ((ln & 3) << 3) ^ ((ln & 32) >> 1);
  const size_t skA = (size_t)128 * K;
  const int sw = (lr & 8) << 2;
  const int aoff = (wm * 64 + lr) * 64 + ((lg * 16) ^ sw);
  const int boff = (wn * 64 + lr) * 64 + ((lg * 16) ^ sw);
  const int NT = K >> 5;

  for (int tt = blockIdx.x; tt < ntiles; tt += gridDim.x) {
    const int wg = (tt & 7) * chunk + (tt >> 3);
    const int m0 = (wg / nx) * 256, n0 = (wg % nx) * 128;

    const bf16_t* gA = A + (size_t)(m0 + lrow) * K + lcol;
    const bf16_t* gB = BT + (size_t)(n0 + lrow) * K + lcol;

    f32x4 acc[4][4] = {};

#pragma unroll
    for (int t = 0; t < 2; ++t) {
      char* d = smem + t * 24576 + wv * 1024;
      __builtin_amdgcn_global_load_lds((const AS1 void*)(gA + t * 32), (AS3 void*)(d), 16, 0, 0);
      __builtin_amdgcn_global_load_lds((const AS1 void*)(gA + skA + t * 32), (AS3 void*)(d + 8192), 16, 0, 0);
      __builtin_amdgcn_global_load_lds((const AS1 void*)(gB + t * 32), (AS3 void*)(d + 16384), 16, 0, 0);
    }
    asm volatile("s_waitcnt vmcnt(3)" ::: "memory");
    __builtin_amdgcn_s_barrier();

    int slot = 0, nslot = 2;
    int t = 0;
    for (; t < NT - 2; ++t) {
      tile_step<true, 3>(smem + slot * 24576, aoff, boff, gA, gB, (t + 2) * 32,
                         skA, smem + nslot * 24576 + wv * 1024, acc);
      slot = (slot == 2) ? 0 : slot + 1;
      nslot = (nslot == 2) ? 0 : nslot + 1;
    }
    tile_step<false, 0>(smem + slot * 24576, aoff, boff, gA, gB, 0, skA, smem, acc);
    slot = (slot == 2) ? 0 : slot + 1;
    tile_step<false, -1>(smem + slot * 24576, aoff, boff, gA, gB, 0, skA, smem, acc);

#pragma unroll
    for (int mi = 0; mi < 4; ++mi)
#pragma unroll
      for (int ni = 0; ni < 4; ++ni) {
        const int col = n0 + wn * 64 + ni * 16 + lr;
        const float bv = bias[col];
#pragma unroll
        for (int i = 0; i < 4; ++i) {
          const int row = m0 + wm * 64 + mi * 16 + lg * 4 + i;
          C[(size_t)row * N + col] = (OutT)(acc[mi][ni][i] + bv);
        }
      }
  }
}

// ---------------- flash attention: causal, 32 heads, d=128, QBLK=128 ----------------
__global__ __launch_bounds__(256, 2) void attn_fwd(
    const bf16_t* __restrict__ qkv, const bf16_t* __restrict__ vt,
    bf16_t* __restrict__ ctx) {
  __shared__ __align__(16) bf16_t Ks[64][136];    // K rows (kv), 272B stride
  __shared__ __align__(16) bf16_t Vts[128][72];   // V^T rows (d), 144B stride

  const int tid = threadIdx.x;
  const int wv = tid >> 6, ln = tid & 63;
  bf16_t* Pl = &Ks[0][0] + wv * (32 * 68);

  const int bid = blockIdx.x;
  const int a = bid >> 3;
  const int hsub = a >> 4;
  const int h  = ((bid & 7) << 2) + hsub;
  const int qt = 15 - (((a & 15) + (hsub << 2)) & 15);
  const int q0 = qt * 128;
  const int lr = ln & 15, lg = ln >> 4;
  const int rbase = q0 + 32 * wv;

  bf16x8 qf[2][4];
#pragma unroll
  for (int rg = 0; rg < 2; ++rg)
#pragma unroll
    for (int kk = 0; kk < 4; ++kk) {
      bf16x8 r = *(const bf16x8*)(qkv + (size_t)(rbase + 16 * rg + lr) * N3 + h * HD + kk * 32 + lg * 8);
#pragma unroll
      for (int j = 0; j < 8; ++j) r[j] = (bf16_t)((float)r[j] * SCALE);
      qf[rg][kk] = r;
    }

  f32x4 oacc[2][8] = {};
  float mrow[2][4], psum[2][4];
#pragma unroll
  for (int rg = 0; rg < 2; ++rg)
#pragma unroll
    for (int i = 0; i < 4; ++i) { mrow[rg][i] = -INFINITY; psum[rg][i] = 0.f; }

  const int ntiles = 2 * qt + 2;
  for (int t = 0; t < ntiles; ++t) {
    const int kv0 = t * 64;
    __syncthreads();
#pragma unroll
    for (int it = 0; it < 4; ++it) {
      int c = tid + it * 256;
      {
        int row = c >> 4, col = (c & 15) * 8;
        *(bf16x8*)&Ks[row][col] =
            *(const bf16x8*)(qkv + (size_t)(kv0 + row) * N3 + HID + h * HD + col);
      }
      {
        int row = c >> 3, col = (c & 7) * 8;
        *(bf16x8*)&Vts[row][col] =
            *(const bf16x8*)(vt + (size_t)(h * HD + row) * S_ + kv0 + col);
      }
    }
    __syncthreads();

    f32x4 sacc[2][4] = {};
#pragma unroll
    for (int kk = 0; kk < 4; ++kk)
#pragma unroll
      for (int ni = 0; ni < 4; ++ni) {
        bf16x8 kf = *(const bf16x8*)&Ks[16 * ni + lr][kk * 32 + lg * 8];
        sacc[0][ni] = __builtin_amdgcn_mfma_f32_16x16x32_bf16(qf[0][kk], kf, sacc[0][ni], 0, 0, 0);
        sacc[1][ni] = __builtin_amdgcn_mfma_f32_16x16x32_bf16(qf[1][kk], kf, sacc[1][ni], 0, 0, 0);
      }

    float p[2][4][4];
    float mx[2][4];
    bool grow = false;
#pragma unroll
    for (int rg = 0; rg < 2; ++rg) {
      const bool needmask = (kv0 + 63 > rbase + 16 * rg);
#pragma unroll
      for (int i = 0; i < 4; ++i) {
        const int row = rbase + 16 * rg + lg * 4 + i;
        float m_ = -INFINITY;
#pragma unroll
        for (int ni = 0; ni < 4; ++ni) {
          float s = sacc[rg][ni][i];
          if (needmask && (kv0 + 16 * ni + lr > row)) s = -INFINITY;
          p[rg][ni][i] = s;
          m_ = fmaxf(m_, s);
        }
        m_ = fmaxf(m_, __shfl_xor(m_, 1, 64));
        m_ = fmaxf(m_, __shfl_xor(m_, 2, 64));
        m_ = fmaxf(m_, __shfl_xor(m_, 4, 64));
        m_ = fmaxf(m_, __shfl_xor(m_, 8, 64));
        mx[rg][i] = m_;
        grow |= (m_ > mrow[rg][i]);
      }
    }
    if (__any(grow)) {
#pragma unroll
      for (int rg = 0; rg < 2; ++rg) {
        float alpha[4];
#pragma unroll
        for (int i = 0; i < 4; ++i) {
          const float mn = fmaxf(mrow[rg][i], mx[rg][i]);
          alpha[i] = __expf(mrow[rg][i] - mn);
          mrow[rg][i] = mn;
          psum[rg][i] *= alpha[i];
        }
#pragma unroll
        for (int nf = 0; nf < 8; ++nf)
#pragma unroll
          for (int i = 0; i < 4; ++i) oacc[rg][nf][i] *= alpha[i];
      }
    }
#pragma unroll
    for (int rg = 0; rg < 2; ++rg)
#pragma unroll
      for (int i = 0; i < 4; ++i) {
        float ps = 0.f;
#pragma unroll
        for (int ni = 0; ni < 4; ++ni) {
          float e = __expf(p[rg][ni][i] - mrow[rg][i]);
          p[rg][ni][i] = e;
          ps += e;
        }
        psum[rg][i] += ps;
      }

    __syncthreads();

#pragma unroll
    for (int rg = 0; rg < 2; ++rg)
#pragma unroll
      for (int ni = 0; ni < 4; ++ni)
#pragma unroll
        for (int i = 0; i < 4; ++i)
          Pl[(16 * rg + lg * 4 + i) * 68 + 16 * ni + lr] = (bf16_t)p[rg][ni][i];

#pragma unroll
    for (int kk2 = 0; kk2 < 2; ++kk2) {
      bf16x8 pf0 = *(const bf16x8*)&Pl[lr * 68 + kk2 * 32 + lg * 8];
      bf16x8 pf1 = *(const bf16x8*)&Pl[(16 + lr) * 68 + kk2 * 32 + lg * 8];
#pragma unroll
      for (int nf = 0; nf < 8; ++nf) {
        bf16x8 vf = *(const bf16x8*)&Vts[16 * nf + lr][kk2 * 32 + lg * 8];
        oacc[0][nf] = __builtin_amdgcn_mfma_f32_16x16x32_bf16(pf0, vf, oacc[0][nf], 0, 0, 0);
        oacc[1][nf] = __builtin_amdgcn_mfma_f32_16x16x32_bf16(pf1, vf, oacc[1][nf], 0, 0, 0);
      }
    }
  }

#pragma unroll
  for (int rg = 0; rg < 2; ++rg) {
#pragma unroll
    for (int i = 0; i < 4; ++i) {
      float s = psum[rg][i];
      s += __shfl_xor(s, 1, 64);
      s += __shfl_xor(s, 2, 64);
      s += __shfl_xor(s, 4, 64);
      s += __shfl_xor(s, 8, 64);
      psum[rg][i] = 1.f / s;
    }
#pragma unroll
    for (int nf = 0; nf < 8; ++nf)
#pragma unroll
      for (int i = 0; i < 4; ++i) {
        int row = rbase + 16 * rg + lg * 4 + i;
        int col = h * HD + 16 * nf + lr;
        ctx[(size_t)row * HID + col] = (bf16_t)(oacc[rg][nf][i] * psum[rg][i]);
      }
  }
}

// ---------------- launcher ----------------
extern "C" void kernel_launch(void* const* d_in, const int* in_sizes, int n_in,
                              void* d_out, int out_size, void* d_ws, size_t ws_size,
                              hipStream_t stream) {
  const float* x    = (const float*)d_in[0];
  const float* wqkv = (const float*)d_in[1];
  const float* bqkv = (const float*)d_in[2];
  const float* ow   = (const float*)d_in[3];
  const float* ob   = (const float*)d_in[4];
  float* out = (float*)d_out;

  char* w = (char*)d_ws;
  bf16_t* xb    = (bf16_t*)(w);                          // S*HID       bf16 (16 MB)
  bf16_t* wqkvT = (bf16_t*)(w + (size_t)16777216);       // N3*HID      bf16 (100.7 MB)
  bf16_t* qkv   = (bf16_t*)(w + (size_t)117440512);      // S*N3        bf16 (50.3 MB)
  bf16_t* vt    = (bf16_t*)(w + (size_t)167772160);      // NH*HD*S     bf16 (16 MB)
  bf16_t* ctx   = (bf16_t*)(w + (size_t)184549376);      // S*HID       bf16 (16 MB)
  bf16_t* owT   = (bf16_t*)(w + (size_t)201326592);      // HID*HID     bf16 (33.6 MB)

  (void)in_sizes; (void)n_in; (void)out_size; (void)ws_size;

  cvt_f32_bf16<<<(S_ * HID / 4 + 255) / 256, 256, 0, stream>>>(x, xb, S_ * HID / 4);
  transcvt64<<<dim3(N3 / 64, HID / 64), 256, 0, stream>>>(wqkv, wqkvT, HID, N3);
  transcvt64<<<dim3(HID / 64, HID / 64), 256, 0, stream>>>(ow, owT, HID, HID);
  // QKV projection: 768 tiles, persistent 512 x 256thr blocks (2/CU, 3 tiles/CU)
  gemm_w<<<512, 256, 73728, stream>>>(xb, wqkvT, bqkv, qkv, S_, N3, HID,
                                      (S_ / 256) * (N3 / 128));
  vtrans<<<dim3(S_ / 32, HD / 32, NH), dim3(32, 8), 0, stream>>>(qkv, vt);
  // attention: QBLK=128, grid 16*32=512 (%8==0), 2 blocks/CU
  attn_fwd<<<(S_ / 128) * NH, 256, 0, stream>>>(qkv, vt, ctx);
  // out projection: 256 tiles, 256 x 512thr blocks (1/CU, 1 tile each)
  gemm_p<float><<<256, 512, 73728, stream>>>(ctx, owT, ob, out, S_, HID, HID,
                                             (S_ / 256) * (HID / 128));
}

// Round 9
// 503.914 us; speedup vs baseline: 1.5429x; 1.0085x over previous
//
#include <hip/hip_runtime.h>
#include <hip/hip_bf16.h>
#include <math.h>

typedef __bf16 bf16_t;
typedef __bf16 bf16x8 __attribute__((ext_vector_type(8)));
typedef float f32x4 __attribute__((ext_vector_type(4)));

#define AS1 __attribute__((address_space(1)))
#define AS3 __attribute__((address_space(3)))

static constexpr int S_  = 2048;
static constexpr int HID = 4096;
static constexpr int NH  = 32;
static constexpr int HD  = 128;
static constexpr int N3  = 3 * HID;           // 12288
static constexpr float SCALE = 0.08838834764831845f;  // 1/sqrt(128)

// ---------------- fp32 -> bf16 convert (vectorized) ----------------
__global__ void cvt_f32_bf16(const float* __restrict__ in, bf16_t* __restrict__ out, int n4) {
  int i = blockIdx.x * blockDim.x + threadIdx.x;
  if (i >= n4) return;
  float4 v = ((const float4*)in)[i];
  union { bf16_t h[4]; short4 s4; } u;
  u.h[0] = (bf16_t)v.x; u.h[1] = (bf16_t)v.y; u.h[2] = (bf16_t)v.z; u.h[3] = (bf16_t)v.w;
  ((short4*)out)[i] = u.s4;
}

// ------- transpose + convert: in[R][C] f32 -> out[C][R] bf16, 64x64 tile -------
__global__ __launch_bounds__(256) void transcvt64(
    const float* __restrict__ in, bf16_t* __restrict__ out, int R, int C) {
  __shared__ float t[64][65];
  const int r0 = blockIdx.y * 64, c0 = blockIdx.x * 64;
  const int tid = threadIdx.x;
  const int rr = tid >> 4, c4 = (tid & 15) * 4;   // 16 rows/iter x 16 float4
#pragma unroll
  for (int it = 0; it < 4; ++it) {
    float4 v = *(const float4*)&in[(size_t)(r0 + rr + it * 16) * C + c0 + c4];
    t[rr + it * 16][c4 + 0] = v.x;
    t[rr + it * 16][c4 + 1] = v.y;
    t[rr + it * 16][c4 + 2] = v.z;
    t[rr + it * 16][c4 + 3] = v.w;
  }
  __syncthreads();
  const int cc = tid >> 3, r8 = (tid & 7) * 8;    // 32 out-rows/iter x 8 chunks
#pragma unroll
  for (int it = 0; it < 2; ++it) {
    const int c = cc + it * 32;
    bf16x8 w;
#pragma unroll
    for (int j = 0; j < 8; ++j) w[j] = (bf16_t)t[r8 + j][c];
    *(bf16x8*)&out[(size_t)(c0 + c) * R + r0 + r8] = w;
  }
}

// ------- per-head V transpose: qkv[s][2*HID + h*HD + d] -> vt[(h*HD+d)*S + s] -------
__global__ void vtrans(const bf16_t* __restrict__ qkv, bf16_t* __restrict__ vt) {
  __shared__ bf16_t t[32][33];
  int h = blockIdx.z;
  int s0 = blockIdx.x * 32, d0 = blockIdx.y * 32;
  int tx = threadIdx.x, ty = threadIdx.y;  // 32 x 8
#pragma unroll
  for (int i = 0; i < 32; i += 8)
    t[ty + i][tx] = qkv[(size_t)(s0 + ty + i) * N3 + 2 * HID + h * HD + d0 + tx];
  __syncthreads();
#pragma unroll
  for (int i = 0; i < 32; i += 8)
    vt[(size_t)(h * HD + d0 + ty + i) * S_ + s0 + tx] = t[tx][ty + i];
}

// ====== gemm_w: 256x128 tile, 4 waves (2Mx2N) of 128x64, ring-3, persistent ======
// SINGLE barrier per K-tile (R9): step = [reads; stage(t+2); vmcnt(6);
// lgkmcnt(0); barrier; MFMA].  Hazard ledger:
//  - slot-t readiness: at barrier(t-1) every wave had vmcnt(6) retire stage(t).
//  - WAR (stage(t+2) overwrites slot(t-1)): reads of slot(t-1) COMPLETED
//    (lgkmcnt(0)) before barrier(t-1); stage(t+2) is issued after barrier(t-1)
//    releases -> no issued-but-unserviced read can see the DMA write.
//  - max inter-wave skew = 1 step -> reads/stage of wave A overlap MFMA of wave B.
template <bool STG, int VMC>
__device__ __forceinline__ void wstep(
    const char* slot, int aoff, int boff,
    const bf16_t* gA, const bf16_t* gB, int kst, size_t row64,
    char* stgA, char* stgB, f32x4 (&acc)[8][4]) {
  bf16x8 a[8], b[4];
#pragma unroll
  for (int mi = 0; mi < 8; ++mi) a[mi] = *(const bf16x8*)(slot + aoff + mi * 1024);
#pragma unroll
  for (int ni = 0; ni < 4; ++ni) b[ni] = *(const bf16x8*)(slot + 16384 + boff + ni * 1024);
  if constexpr (STG) {
#pragma unroll
    for (int i = 0; i < 4; ++i)
      __builtin_amdgcn_global_load_lds((const AS1 void*)(gA + i * row64 + kst),
                                       (AS3 void*)(stgA + i * 4096), 16, 0, 0);
#pragma unroll
    for (int j = 0; j < 2; ++j)
      __builtin_amdgcn_global_load_lds((const AS1 void*)(gB + j * row64 + kst),
                                       (AS3 void*)(stgB + j * 4096), 16, 0, 0);
  }
  if constexpr (VMC == 6)      asm volatile("s_waitcnt vmcnt(6)" ::: "memory");
  else if constexpr (VMC == 0) asm volatile("s_waitcnt vmcnt(0)" ::: "memory");
  asm volatile("s_waitcnt lgkmcnt(0)" ::: "memory");  // own reads COMPLETE pre-barrier
  __builtin_amdgcn_s_barrier();
  __builtin_amdgcn_s_setprio(1);
#pragma unroll
  for (int mi = 0; mi < 8; ++mi)
#pragma unroll
    for (int ni = 0; ni < 4; ++ni)
      acc[mi][ni] = __builtin_amdgcn_mfma_f32_16x16x32_bf16(a[mi], b[ni], acc[mi][ni], 0, 0, 0);
  __builtin_amdgcn_s_setprio(0);
}

__global__ __launch_bounds__(256, 2) void gemm_w(
    const bf16_t* __restrict__ A, const bf16_t* __restrict__ BT,
    const float* __restrict__ bias, bf16_t* __restrict__ C,
    int M, int N, int K, int ntiles) {
  extern __shared__ char smem[];
  const int tid = threadIdx.x;
  const int wv = tid >> 6, ln = tid & 63;
  const int lr = ln & 15, lg = ln >> 4;
  const int wm = wv >> 1, wn = wv & 1;

  const int nx = N >> 7;
  const int chunk = ntiles >> 3;  // ntiles % 8 == 0

  // staging lane geometry: dest byte (region) = wv*1024 + i*4096 + ln*16
  //   -> row = wv*16 + i*64 + (ln>>2); row-bit3 = ln&32 -> same inverse swizzle
  const int lrow = wv * 16 + (ln >> 2);
  const int lcol = ((ln & 3) << 3) ^ ((ln & 32) >> 1);
  const size_t row64 = (size_t)64 * K;
  // swizzled frag-read offsets: byte = row*64 + (lg*16 ^ (32 if row&8 (=lr&8)))
  const int sw = (lr & 8) << 2;
  const int aoff = (wm * 128 + lr) * 64 + ((lg * 16) ^ sw);
  const int boff = (wn * 64 + lr) * 64 + ((lg * 16) ^ sw);
  const int NT = K >> 5;

  for (int tt = blockIdx.x; tt < ntiles; tt += gridDim.x) {
    const int wg = (tt & 7) * chunk + (tt >> 3);  // XCD-contiguous chunks
    const int m0 = (wg / nx) * 256, n0 = (wg % nx) * 128;

    const bf16_t* gA = A + (size_t)(m0 + lrow) * K + lcol;
    const bf16_t* gB = BT + (size_t)(n0 + lrow) * K + lcol;

    f32x4 acc[8][4] = {};

    // prologue: stage tiles 0,1 (12 loads/wave); vmcnt(6) retires t0, keeps t1
#pragma unroll
    for (int t = 0; t < 2; ++t) {
      char* dA = smem + t * 24576 + wv * 1024;
      char* dB = dA + 16384;
#pragma unroll
      for (int i = 0; i < 4; ++i)
        __builtin_amdgcn_global_load_lds((const AS1 void*)(gA + i * row64 + t * 32),
                                         (AS3 void*)(dA + i * 4096), 16, 0, 0);
#pragma unroll
      for (int j = 0; j < 2; ++j)
        __builtin_amdgcn_global_load_lds((const AS1 void*)(gB + j * row64 + t * 32),
                                         (AS3 void*)(dB + j * 4096), 16, 0, 0);
    }
    asm volatile("s_waitcnt vmcnt(6)" ::: "memory");
    __builtin_amdgcn_s_barrier();

    int slot = 0, nslot = 2;
    int t = 0;
    for (; t < NT - 2; ++t) {
      char* sb = smem + nslot * 24576 + wv * 1024;
      wstep<true, 6>(smem + slot * 24576, aoff, boff, gA, gB, (t + 2) * 32,
                     row64, sb, sb + 16384, acc);
      slot = (slot == 2) ? 0 : slot + 1;
      nslot = (nslot == 2) ? 0 : nslot + 1;
    }
    wstep<false, 0>(smem + slot * 24576, aoff, boff, gA, gB, 0, row64, smem, smem, acc);
    slot = (slot == 2) ? 0 : slot + 1;
    wstep<false, -1>(smem + slot * 24576, aoff, boff, gA, gB, 0, row64, smem, smem, acc);

    // epilogue
#pragma unroll
    for (int mi = 0; mi < 8; ++mi)
#pragma unroll
      for (int ni = 0; ni < 4; ++ni) {
        const int col = n0 + wn * 64 + ni * 16 + lr;
        const float bv = bias[col];
#pragma unroll
        for (int i = 0; i < 4; ++i) {
          const int row = m0 + wm * 128 + mi * 16 + lg * 4 + i;
          C[(size_t)row * N + col] = (bf16_t)(acc[mi][ni][i] + bv);
        }
      }
  }
}

// ====== 256x128-tile GEMM, 8 waves of 64x64, ring-3, persistent (out-proj) ======
// Same single-barrier step structure; 3 loads/tile/wave -> vmcnt(3).
template <bool STG, int VMC>
__device__ __forceinline__ void tile_step(
    const char* slot, int aoff, int boff,
    const bf16_t* gA, const bf16_t* gB, int kst, size_t skA,
    char* stg_dst, f32x4 (&acc)[4][4]) {
  bf16x8 a[4], b[4];
#pragma unroll
  for (int mi = 0; mi < 4; ++mi) a[mi] = *(const bf16x8*)(slot + aoff + mi * 1024);
#pragma unroll
  for (int ni = 0; ni < 4; ++ni) b[ni] = *(const bf16x8*)(slot + 16384 + boff + ni * 1024);
  if constexpr (STG) {
    __builtin_amdgcn_global_load_lds((const AS1 void*)(gA + kst), (AS3 void*)(stg_dst), 16, 0, 0);
    __builtin_amdgcn_global_load_lds((const AS1 void*)(gA + skA + kst), (AS3 void*)(stg_dst + 8192), 16, 0, 0);
    __builtin_amdgcn_global_load_lds((const AS1 void*)(gB + kst), (AS3 void*)(stg_dst + 16384), 16, 0, 0);
  }
  if constexpr (VMC == 3)      asm volatile("s_waitcnt vmcnt(3)" ::: "memory");
  else if constexpr (VMC == 0) asm volatile("s_waitcnt vmcnt(0)" ::: "memory");
  asm volatile("s_waitcnt lgkmcnt(0)" ::: "memory");
  __builtin_amdgcn_s_barrier();
  __builtin_amdgcn_s_setprio(1);
#pragma unroll
  for (int mi = 0; mi < 4; ++mi)
#pragma unroll
    for (int ni = 0; ni < 4; ++ni)
      acc[mi][ni] = __builtin_amdgcn_mfma_f32_16x16x32_bf16(a[mi], b[ni], acc[mi][ni], 0, 0, 0);
  __builtin_amdgcn_s_setprio(0);
}

template <typename OutT>
__global__ __launch_bounds__(512, 4) void gemm_p(
    const bf16_t* __restrict__ A, const bf16_t* __restrict__ BT,
    const float* __restrict__ bias, OutT* __restrict__ C,
    int M, int N, int K, int ntiles) {
  extern __shared__ char smem[];
  const int tid = threadIdx.x;
  const int wv = tid >> 6, ln = tid & 63;
  const int lr = ln & 15, lg = ln >> 4;
  const int wm = wv >> 1, wn = wv & 1;

  const int nx = N >> 7;
  const int chunk = ntiles >> 3;

  const int lrow = wv * 16 + (ln >> 2);
  const int lcol = ((ln & 3) << 3) ^ ((ln & 32) >> 1);
  const size_t skA = (size_t)128 * K;
  const int sw = (lr & 8) << 2;
  const int aoff = (wm * 64 + lr) * 64 + ((lg * 16) ^ sw);
  const int boff = (wn * 64 + lr) * 64 + ((lg * 16) ^ sw);
  const int NT = K >> 5;

  for (int tt = blockIdx.x; tt < ntiles; tt += gridDim.x) {
    const int wg = (tt & 7) * chunk + (tt >> 3);
    const int m0 = (wg / nx) * 256, n0 = (wg % nx) * 128;

    const bf16_t* gA = A + (size_t)(m0 + lrow) * K + lcol;
    const bf16_t* gB = BT + (size_t)(n0 + lrow) * K + lcol;

    f32x4 acc[4][4] = {};

#pragma unroll
    for (int t = 0; t < 2; ++t) {
      char* d = smem + t * 24576 + wv * 1024;
      __builtin_amdgcn_global_load_lds((const AS1 void*)(gA + t * 32), (AS3 void*)(d), 16, 0, 0);
      __builtin_amdgcn_global_load_lds((const AS1 void*)(gA + skA + t * 32), (AS3 void*)(d + 8192), 16, 0, 0);
      __builtin_amdgcn_global_load_lds((const AS1 void*)(gB + t * 32), (AS3 void*)(d + 16384), 16, 0, 0);
    }
    asm volatile("s_waitcnt vmcnt(3)" ::: "memory");
    __builtin_amdgcn_s_barrier();

    int slot = 0, nslot = 2;
    int t = 0;
    for (; t < NT - 2; ++t) {
      tile_step<true, 3>(smem + slot * 24576, aoff, boff, gA, gB, (t + 2) * 32,
                         skA, smem + nslot * 24576 + wv * 1024, acc);
      slot = (slot == 2) ? 0 : slot + 1;
      nslot = (nslot == 2) ? 0 : nslot + 1;
    }
    tile_step<false, 0>(smem + slot * 24576, aoff, boff, gA, gB, 0, skA, smem, acc);
    slot = (slot == 2) ? 0 : slot + 1;
    tile_step<false, -1>(smem + slot * 24576, aoff, boff, gA, gB, 0, skA, smem, acc);

#pragma unroll
    for (int mi = 0; mi < 4; ++mi)
#pragma unroll
      for (int ni = 0; ni < 4; ++ni) {
        const int col = n0 + wn * 64 + ni * 16 + lr;
        const float bv = bias[col];
#pragma unroll
        for (int i = 0; i < 4; ++i) {
          const int row = m0 + wm * 64 + mi * 16 + lg * 4 + i;
          C[(size_t)row * N + col] = (OutT)(acc[mi][ni][i] + bv);
        }
      }
  }
}

// ---------------- flash attention: causal, 32 heads, d=128, QBLK=128 ----------------
__global__ __launch_bounds__(256, 2) void attn_fwd(
    const bf16_t* __restrict__ qkv, const bf16_t* __restrict__ vt,
    bf16_t* __restrict__ ctx) {
  __shared__ __align__(16) bf16_t Ks[64][136];    // K rows (kv), 272B stride
  __shared__ __align__(16) bf16_t Vts[128][72];   // V^T rows (d), 144B stride

  const int tid = threadIdx.x;
  const int wv = tid >> 6, ln = tid & 63;
  bf16_t* Pl = &Ks[0][0] + wv * (32 * 68);

  const int bid = blockIdx.x;
  const int a = bid >> 3;
  const int hsub = a >> 4;
  const int h  = ((bid & 7) << 2) + hsub;
  const int qt = 15 - (((a & 15) + (hsub << 2)) & 15);
  const int q0 = qt * 128;
  const int lr = ln & 15, lg = ln >> 4;
  const int rbase = q0 + 32 * wv;

  bf16x8 qf[2][4];
#pragma unroll
  for (int rg = 0; rg < 2; ++rg)
#pragma unroll
    for (int kk = 0; kk < 4; ++kk) {
      bf16x8 r = *(const bf16x8*)(qkv + (size_t)(rbase + 16 * rg + lr) * N3 + h * HD + kk * 32 + lg * 8);
#pragma unroll
      for (int j = 0; j < 8; ++j) r[j] = (bf16_t)((float)r[j] * SCALE);
      qf[rg][kk] = r;
    }

  f32x4 oacc[2][8] = {};
  float mrow[2][4], psum[2][4];
#pragma unroll
  for (int rg = 0; rg < 2; ++rg)
#pragma unroll
    for (int i = 0; i < 4; ++i) { mrow[rg][i] = -INFINITY; psum[rg][i] = 0.f; }

  const int ntiles = 2 * qt + 2;
  for (int t = 0; t < ntiles; ++t) {
    const int kv0 = t * 64;
    __syncthreads();
#pragma unroll
    for (int it = 0; it < 4; ++it) {
      int c = tid + it * 256;
      {
        int row = c >> 4, col = (c & 15) * 8;
        *(bf16x8*)&Ks[row][col] =
            *(const bf16x8*)(qkv + (size_t)(kv0 + row) * N3 + HID + h * HD + col);
      }
      {
        int row = c >> 3, col = (c & 7) * 8;
        *(bf16x8*)&Vts[row][col] =
            *(const bf16x8*)(vt + (size_t)(h * HD + row) * S_ + kv0 + col);
      }
    }
    __syncthreads();

    f32x4 sacc[2][4] = {};
#pragma unroll
    for (int kk = 0; kk < 4; ++kk)
#pragma unroll
      for (int ni = 0; ni < 4; ++ni) {
        bf16x8 kf = *(const bf16x8*)&Ks[16 * ni + lr][kk * 32 + lg * 8];
        sacc[0][ni] = __builtin_amdgcn_mfma_f32_16x16x32_bf16(qf[0][kk], kf, sacc[0][ni], 0, 0, 0);
        sacc[1][ni] = __builtin_amdgcn_mfma_f32_16x16x32_bf16(qf[1][kk], kf, sacc[1][ni], 0, 0, 0);
      }

    float p[2][4][4];
    float mx[2][4];
    bool grow = false;
#pragma unroll
    for (int rg = 0; rg < 2; ++rg) {
      const bool needmask = (kv0 + 63 > rbase + 16 * rg);
#pragma unroll
      for (int i = 0; i < 4; ++i) {
        const int row = rbase + 16 * rg + lg * 4 + i;
        float m_ = -INFINITY;
#pragma unroll
        for (int ni = 0; ni < 4; ++ni) {
          float s = sacc[rg][ni][i];
          if (needmask && (kv0 + 16 * ni + lr > row)) s = -INFINITY;
          p[rg][ni][i] = s;
          m_ = fmaxf(m_, s);
        }
        m_ = fmaxf(m_, __shfl_xor(m_, 1, 64));
        m_ = fmaxf(m_, __shfl_xor(m_, 2, 64));
        m_ = fmaxf(m_, __shfl_xor(m_, 4, 64));
        m_ = fmaxf(m_, __shfl_xor(m_, 8, 64));
        mx[rg][i] = m_;
        grow |= (m_ > mrow[rg][i]);
      }
    }
    if (__any(grow)) {
#pragma unroll
      for (int rg = 0; rg < 2; ++rg) {
        float alpha[4];
#pragma unroll
        for (int i = 0; i < 4; ++i) {
          const float mn = fmaxf(mrow[rg][i], mx[rg][i]);
          alpha[i] = __expf(mrow[rg][i] - mn);
          mrow[rg][i] = mn;
          psum[rg][i] *= alpha[i];
        }
#pragma unroll
        for (int nf = 0; nf < 8; ++nf)
#pragma unroll
          for (int i = 0; i < 4; ++i) oacc[rg][nf][i] *= alpha[i];
      }
    }
#pragma unroll
    for (int rg = 0; rg < 2; ++rg)
#pragma unroll
      for (int i = 0; i < 4; ++i) {
        float ps = 0.f;
#pragma unroll
        for (int ni = 0; ni < 4; ++ni) {
          float e = __expf(p[rg][ni][i] - mrow[rg][i]);
          p[rg][ni][i] = e;
          ps += e;
        }
        psum[rg][i] += ps;
      }

    __syncthreads();

#pragma unroll
    for (int rg = 0; rg < 2; ++rg)
#pragma unroll
      for (int ni = 0; ni < 4; ++ni)
#pragma unroll
        for (int i = 0; i < 4; ++i)
          Pl[(16 * rg + lg * 4 + i) * 68 + 16 * ni + lr] = (bf16_t)p[rg][ni][i];

#pragma unroll
    for (int kk2 = 0; kk2 < 2; ++kk2) {
      bf16x8 pf0 = *(const bf16x8*)&Pl[lr * 68 + kk2 * 32 + lg * 8];
      bf16x8 pf1 = *(const bf16x8*)&Pl[(16 + lr) * 68 + kk2 * 32 + lg * 8];
#pragma unroll
      for (int nf = 0; nf < 8; ++nf) {
        bf16x8 vf = *(const bf16x8*)&Vts[16 * nf + lr][kk2 * 32 + lg * 8];
        oacc[0][nf] = __builtin_amdgcn_mfma_f32_16x16x32_bf16(pf0, vf, oacc[0][nf], 0, 0, 0);
        oacc[1][nf] = __builtin_amdgcn_mfma_f32_16x16x32_bf16(pf1, vf, oacc[1][nf], 0, 0, 0);
      }
    }
  }

#pragma unroll
  for (int rg = 0; rg < 2; ++rg) {
#pragma unroll
    for (int i = 0; i < 4; ++i) {
      float s = psum[rg][i];
      s += __shfl_xor(s, 1, 64);
      s += __shfl_xor(s, 2, 64);
      s += __shfl_xor(s, 4, 64);
      s += __shfl_xor(s, 8, 64);
      psum[rg][i] = 1.f / s;
    }
#pragma unroll
    for (int nf = 0; nf < 8; ++nf)
#pragma unroll
      for (int i = 0; i < 4; ++i) {
        int row = rbase + 16 * rg + lg * 4 + i;
        int col = h * HD + 16 * nf + lr;
        ctx[(size_t)row * HID + col] = (bf16_t)(oacc[rg][nf][i] * psum[rg][i]);
      }
  }
}

// ---------------- launcher ----------------
extern "C" void kernel_launch(void* const* d_in, const int* in_sizes, int n_in,
                              void* d_out, int out_size, void* d_ws, size_t ws_size,
                              hipStream_t stream) {
  const float* x    = (const float*)d_in[0];
  const float* wqkv = (const float*)d_in[1];
  const float* bqkv = (const float*)d_in[2];
  const float* ow   = (const float*)d_in[3];
  const float* ob   = (const float*)d_in[4];
  float* out = (float*)d_out;

  char* w = (char*)d_ws;
  bf16_t* xb    = (bf16_t*)(w);                          // S*HID       bf16 (16 MB)
  bf16_t* wqkvT = (bf16_t*)(w + (size_t)16777216);       // N3*HID      bf16 (100.7 MB)
  bf16_t* qkv   = (bf16_t*)(w + (size_t)117440512);      // S*N3        bf16 (50.3 MB)
  bf16_t* vt    = (bf16_t*)(w + (size_t)167772160);      // NH*HD*S     bf16 (16 MB)
  bf16_t* ctx   = (bf16_t*)(w + (size_t)184549376);      // S*HID       bf16 (16 MB)
  bf16_t* owT   = (bf16_t*)(w + (size_t)201326592);      // HID*HID     bf16 (33.6 MB)

  (void)in_sizes; (void)n_in; (void)out_size; (void)ws_size;

  cvt_f32_bf16<<<(S_ * HID / 4 + 255) / 256, 256, 0, stream>>>(x, xb, S_ * HID / 4);
  transcvt64<<<dim3(N3 / 64, HID / 64), 256, 0, stream>>>(wqkv, wqkvT, HID, N3);
  transcvt64<<<dim3(HID / 64, HID / 64), 256, 0, stream>>>(ow, owT, HID, HID);
  // QKV projection: 768 tiles, persistent 512 x 256thr blocks (2/CU, 3 tiles/CU)
  gemm_w<<<512, 256, 73728, stream>>>(xb, wqkvT, bqkv, qkv, S_, N3, HID,
                                      (S_ / 256) * (N3 / 128));
  vtrans<<<dim3(S_ / 32, HD / 32, NH), dim3(32, 8), 0, stream>>>(qkv, vt);
  // attention: QBLK=128, grid 16*32=512 (%8==0), 2 blocks/CU
  attn_fwd<<<(S_ / 128) * NH, 256, 0, stream>>>(qkv, vt, ctx);
  // out projection: 256 tiles, 256 x 512thr blocks (1/CU, 1 tile each)
  gemm_p<float><<<256, 512, 73728, stream>>>(ctx, owT, ob, out, S_, HID, HID,
                                             (S_ / 256) * (HID / 128));
}